// Round 1
// baseline (1390.266 us; speedup 1.0000x reference)
//
#include <hip/hip_runtime.h>
#include <math.h>

#define N_DRUG 20000
#define N_PROT 30000
#define NN (N_DRUG + N_PROT)
#define F_DRUG 128
#define F_PROT 256
#define H 64
#define NE 1600000
#define NL 200000
#define LAYERS 3

// ---------------- degree histogram over dst ----------------
__global__ void k_hist(const int* __restrict__ ei, int* __restrict__ cnt) {
    int e = blockIdx.x * blockDim.x + threadIdx.x;
    if (e < NE) atomicAdd(&cnt[ei[NE + e]], 1);
}

// ---------------- dis = rsqrt(deg+1) ----------------
__global__ void k_dis(const int* __restrict__ cnt, float* __restrict__ dis) {
    int i = blockIdx.x * blockDim.x + threadIdx.x;
    if (i < NN) dis[i] = rsqrtf((float)cnt[i] + 1.0f);
}

// ---------------- single-block exclusive scan -> row_ptr, cursor ----------------
#define SCAN_T 1024
__global__ void k_scan(const int* __restrict__ cnt, int* __restrict__ rp,
                       int* __restrict__ cur) {
    __shared__ int sums[SCAN_T];
    int t = threadIdx.x;
    const int chunk = (NN + SCAN_T - 1) / SCAN_T;  // 49
    int lo = t * chunk;
    int hi = lo + chunk; if (hi > NN) hi = NN;
    int s = 0;
    for (int i = lo; i < hi; ++i) s += cnt[i];
    sums[t] = s;
    __syncthreads();
    // Hillis-Steele inclusive scan
    for (int off = 1; off < SCAN_T; off <<= 1) {
        int v = sums[t];
        int u = (t >= off) ? sums[t - off] : 0;
        __syncthreads();
        sums[t] = v + u;
        __syncthreads();
    }
    int run = (t > 0) ? sums[t - 1] : 0;   // exclusive prefix of this chunk
    for (int i = lo; i < hi; ++i) {
        rp[i] = run; cur[i] = run;
        run += cnt[i];
    }
    if (t == SCAN_T - 1) rp[NN] = run;     // == NE
}

// ---------------- scatter edges into CSR ----------------
__global__ void k_scatter(const int* __restrict__ ei, const float* __restrict__ dis,
                          int* __restrict__ cur, int* __restrict__ csr_src,
                          float* __restrict__ csr_w) {
    int e = blockIdx.x * blockDim.x + threadIdx.x;
    if (e < NE) {
        int s = ei[e];
        int d = ei[NE + e];
        int p = atomicAdd(&cur[d], 1);
        csr_src[p] = s;
        csr_w[p] = dis[s];
    }
}

// ---------------- typed input projection + relu: out[r] = relu(X[r]@W + b) ----------------
template <int F>
__global__ void k_proj(const float* __restrict__ X, const float* __restrict__ W,
                       const float* __restrict__ b, float* __restrict__ out,
                       int rows, int row_off) {
    __shared__ float Ws[F * H];
    for (int i = threadIdx.x; i < F * H; i += blockDim.x) Ws[i] = W[i];
    __syncthreads();
    int lane = threadIdx.x & 63;
    int warp = threadIdx.x >> 6;
    int nwarp = blockDim.x >> 6;
    float bl = b[lane];
    for (int r = blockIdx.x * nwarp + warp; r < rows; r += gridDim.x * nwarp) {
        float acc = bl;
        const float* xr = X + (size_t)r * F;
        for (int f0 = 0; f0 < F; f0 += 64) {
            float xv = xr[f0 + lane];
            #pragma unroll
            for (int j = 0; j < 64; ++j) {
                float xf = __shfl(xv, j);
                acc += xf * Ws[(f0 + j) * H + lane];
            }
        }
        out[(size_t)(row_off + r) * H + lane] = fmaxf(acc, 0.f);
    }
}

// ---------------- conv GEMM: xw = x @ W  (64x64) ----------------
__global__ void k_conv(const float* __restrict__ X, const float* __restrict__ W,
                       float* __restrict__ out) {
    __shared__ float Ws[H * H];
    for (int i = threadIdx.x; i < H * H; i += blockDim.x) Ws[i] = W[i];
    __syncthreads();
    int lane = threadIdx.x & 63;
    int warp = threadIdx.x >> 6;
    int nwarp = blockDim.x >> 6;
    for (int r = blockIdx.x * nwarp + warp; r < NN; r += gridDim.x * nwarp) {
        float xv = X[(size_t)r * H + lane];
        float acc = 0.f;
        #pragma unroll
        for (int j = 0; j < 64; ++j) {
            acc += __shfl(xv, j) * Ws[j * H + lane];
        }
        out[(size_t)r * H + lane] = acc;
    }
}

// ---------------- SpMM + self-term + bias + relu (fused layer update) ----------------
__global__ void k_spmm(const int* __restrict__ rp, const int* __restrict__ csr_src,
                       const float* __restrict__ csr_w, const float* __restrict__ dis,
                       const float* __restrict__ xw, const float* __restrict__ bias,
                       float* __restrict__ xout) {
    int lane = threadIdx.x & 63;
    int warp = threadIdx.x >> 6;
    int nwarp = blockDim.x >> 6;
    int d = blockIdx.x * nwarp + warp;
    if (d >= NN) return;
    int beg = rp[d], end = rp[d + 1];
    float dd = dis[d];
    float acc = dd * xw[(size_t)d * H + lane];   // self term (scaled by dd again below)
    for (int b0 = beg; b0 < end; b0 += 64) {
        int n = end - b0;
        int sv = 0; float wv = 0.f;
        if (lane < n) {
            sv = csr_src[b0 + lane];
            wv = csr_w[b0 + lane];
        }
        int m = n < 64 ? n : 64;
        for (int j = 0; j < m; ++j) {
            int s = __shfl(sv, j);
            float w = __shfl(wv, j);
            acc += w * xw[(size_t)s * H + lane];
        }
    }
    xout[(size_t)d * H + lane] = fmaxf(dd * acc + bias[lane], 0.f);
}

// ---------------- per-node score y[i] = x[i]@lin_W + lin_b ----------------
__global__ void k_y(const float* __restrict__ x, const float* __restrict__ lw,
                    const float* __restrict__ lb, float* __restrict__ y) {
    int lane = threadIdx.x & 63;
    int warp = threadIdx.x >> 6;
    int nwarp = blockDim.x >> 6;
    int i = blockIdx.x * nwarp + warp;
    if (i >= NN) return;
    float v = x[(size_t)i * H + lane] * lw[lane];
    for (int off = 32; off > 0; off >>= 1) v += __shfl_down(v, off);
    if (lane == 0) y[i] = v + lb[0];
}

// ---------------- edge scoring: sigmoid(y[src]*y[dst]) ----------------
__global__ void k_out(const float* __restrict__ y, const int* __restrict__ ls,
                      const int* __restrict__ ld, float* __restrict__ out) {
    int e = blockIdx.x * blockDim.x + threadIdx.x;
    if (e < NL) {
        float z = y[ls[e]] * y[ld[e]];
        out[e] = 1.f / (1.f + __expf(-z));
    }
}

extern "C" void kernel_launch(void* const* d_in, const int* in_sizes, int n_in,
                              void* d_out, int out_size, void* d_ws, size_t ws_size,
                              hipStream_t stream) {
    const float* x_drug = (const float*)d_in[0];
    const float* x_prot = (const float*)d_in[1];
    const float* W_drug = (const float*)d_in[2];
    const float* b_drug = (const float*)d_in[3];
    const float* W_prot = (const float*)d_in[4];
    const float* b_prot = (const float*)d_in[5];
    const float* conv_W = (const float*)d_in[6];
    const float* conv_b = (const float*)d_in[7];
    const float* lin_W  = (const float*)d_in[8];
    const float* lin_b  = (const float*)d_in[9];
    const int*   ei     = (const int*)d_in[10];
    const int*   lsrc   = (const int*)d_in[11];
    const int*   ldst   = (const int*)d_in[12];
    float* out = (float*)d_out;

    char* w = (char*)d_ws;
    int*   cnt     = (int*)w;    w += (size_t)NN * 4;
    int*   rp      = (int*)w;    w += (size_t)(NN + 4) * 4;
    int*   cur     = (int*)w;    w += (size_t)NN * 4;
    int*   csr_src = (int*)w;    w += (size_t)NE * 4;
    float* csr_w   = (float*)w;  w += (size_t)NE * 4;
    float* dis     = (float*)w;  w += (size_t)NN * 4;
    float* xbuf    = (float*)w;  w += (size_t)NN * H * 4;
    float* xwbuf   = (float*)w;  w += (size_t)NN * H * 4;
    float* y       = (float*)w;  w += (size_t)NN * 4;

    hipMemsetAsync(cnt, 0, (size_t)NN * 4, stream);
    k_hist<<<(NE + 255) / 256, 256, 0, stream>>>(ei, cnt);
    k_dis<<<(NN + 255) / 256, 256, 0, stream>>>(cnt, dis);
    k_scan<<<1, SCAN_T, 0, stream>>>(cnt, rp, cur);
    k_scatter<<<(NE + 255) / 256, 256, 0, stream>>>(ei, dis, cur, csr_src, csr_w);

    k_proj<F_DRUG><<<1024, 256, 0, stream>>>(x_drug, W_drug, b_drug, xbuf, N_DRUG, 0);
    k_proj<F_PROT><<<1024, 256, 0, stream>>>(x_prot, W_prot, b_prot, xbuf, N_PROT, N_DRUG);

    for (int l = 0; l < LAYERS; ++l) {
        k_conv<<<2048, 256, 0, stream>>>(xbuf, conv_W + (size_t)l * H * H, xwbuf);
        k_spmm<<<(NN + 3) / 4, 256, 0, stream>>>(rp, csr_src, csr_w, dis, xwbuf,
                                                 conv_b + (size_t)l * H, xbuf);
    }

    k_y<<<(NN + 3) / 4, 256, 0, stream>>>(xbuf, lin_W, lin_b, y);
    k_out<<<(NL + 255) / 256, 256, 0, stream>>>(y, lsrc, ldst, out);
}

// Round 2
// 763.318 us; speedup vs baseline: 1.8213x; 1.8213x over previous
//
#include <hip/hip_runtime.h>
#include <math.h>

#define N_DRUG 20000
#define N_PROT 30000
#define NN (N_DRUG + N_PROT)
#define F_DRUG 128
#define F_PROT 256
#define H 64
#define NE 1600000
#define NL 200000
#define LAYERS 3

// ---------------- degree histogram over dst ----------------
__global__ void k_hist(const int* __restrict__ ei, int* __restrict__ cnt) {
    int e = blockIdx.x * blockDim.x + threadIdx.x;
    if (e < NE) atomicAdd(&cnt[ei[NE + e]], 1);
}

// ---------------- dis = rsqrt(deg+1) ----------------
__global__ void k_dis(const int* __restrict__ cnt, float* __restrict__ dis) {
    int i = blockIdx.x * blockDim.x + threadIdx.x;
    if (i < NN) dis[i] = rsqrtf((float)cnt[i] + 1.0f);
}

// ---------------- single-block exclusive scan -> row_ptr, cursor ----------------
#define SCAN_T 1024
__global__ void k_scan(const int* __restrict__ cnt, int* __restrict__ rp,
                       int* __restrict__ cur) {
    __shared__ int sums[SCAN_T];
    int t = threadIdx.x;
    const int chunk = (NN + SCAN_T - 1) / SCAN_T;  // 49
    int lo = t * chunk;
    int hi = lo + chunk; if (hi > NN) hi = NN;
    int s = 0;
    for (int i = lo; i < hi; ++i) s += cnt[i];
    sums[t] = s;
    __syncthreads();
    for (int off = 1; off < SCAN_T; off <<= 1) {
        int v = sums[t];
        int u = (t >= off) ? sums[t - off] : 0;
        __syncthreads();
        sums[t] = v + u;
        __syncthreads();
    }
    int run = (t > 0) ? sums[t - 1] : 0;
    for (int i = lo; i < hi; ++i) {
        rp[i] = run; cur[i] = run;
        run += cnt[i];
    }
    if (t == SCAN_T - 1) rp[NN] = run;
}

// ---------------- scatter edges into CSR ----------------
__global__ void k_scatter(const int* __restrict__ ei, const float* __restrict__ dis,
                          int* __restrict__ cur, int* __restrict__ csr_src,
                          float* __restrict__ csr_w) {
    int e = blockIdx.x * blockDim.x + threadIdx.x;
    if (e < NE) {
        int s = ei[e];
        int d = ei[NE + e];
        int p = atomicAdd(&cur[d], 1);
        csr_src[p] = s;
        csr_w[p] = dis[s];
    }
}

// ---------------- register-blocked tiled GEMM: out = [relu](X @ W + b) ----------------
// Block: 256 threads, 128 rows x 64 cols. Thread: 8 rows x 4 cols accumulator.
#define KC 64
template <int F, bool RELU>
__global__ void k_gemm(const float* __restrict__ X, const float* __restrict__ W,
                       const float* __restrict__ bias, float* __restrict__ out,
                       int rows, int row_off) {
    __shared__ float Xs[128][KC + 1];  // +1 pad: column reads hit distinct banks
    __shared__ float Ws[KC][H];
    int tid = threadIdx.x;
    int r0 = blockIdx.x * 128;
    int rg = tid >> 4;        // 0..15 -> rows rg*8 .. rg*8+7
    int cg = tid & 15;        // 0..15 -> cols cg*4 .. cg*4+3
    float acc[8][4];
    #pragma unroll
    for (int i = 0; i < 8; ++i)
        #pragma unroll
        for (int j = 0; j < 4; ++j) acc[i][j] = 0.f;

    for (int k0 = 0; k0 < F; k0 += KC) {
        // stage X tile [128][64] (coalesced: consecutive tid = consecutive f)
        #pragma unroll
        for (int idx = tid; idx < 128 * KC; idx += 256) {
            int r = idx >> 6, f = idx & 63;
            int gr = r0 + r;
            Xs[r][f] = (gr < rows) ? X[(size_t)gr * F + k0 + f] : 0.f;
        }
        // stage W tile [64][64]
        #pragma unroll
        for (int idx = tid; idx < KC * H; idx += 256) {
            int k = idx >> 6, c = idx & 63;
            Ws[k][c] = W[(size_t)(k0 + k) * H + c];
        }
        __syncthreads();
        #pragma unroll 4
        for (int k = 0; k < KC; ++k) {
            float a[8];
            #pragma unroll
            for (int i = 0; i < 8; ++i) a[i] = Xs[rg * 8 + i][k];
            float4 bb = *(const float4*)&Ws[k][cg * 4];
            #pragma unroll
            for (int i = 0; i < 8; ++i) {
                acc[i][0] += a[i] * bb.x;
                acc[i][1] += a[i] * bb.y;
                acc[i][2] += a[i] * bb.z;
                acc[i][3] += a[i] * bb.w;
            }
        }
        __syncthreads();
    }
    // epilogue: float4 stores
    float4 bv = make_float4(0.f, 0.f, 0.f, 0.f);
    if (bias) bv = *(const float4*)&bias[cg * 4];
    #pragma unroll
    for (int i = 0; i < 8; ++i) {
        int gr = r0 + rg * 8 + i;
        if (gr < rows) {
            float4 v;
            v.x = acc[i][0] + bv.x;
            v.y = acc[i][1] + bv.y;
            v.z = acc[i][2] + bv.z;
            v.w = acc[i][3] + bv.w;
            if (RELU) {
                v.x = fmaxf(v.x, 0.f); v.y = fmaxf(v.y, 0.f);
                v.z = fmaxf(v.z, 0.f); v.w = fmaxf(v.w, 0.f);
            }
            *(float4*)&out[(size_t)(row_off + gr) * H + cg * 4] = v;
        }
    }
}

// ---------------- SpMM + self-term + bias + relu (fused layer update) ----------------
__global__ void k_spmm(const int* __restrict__ rp, const int* __restrict__ csr_src,
                       const float* __restrict__ csr_w, const float* __restrict__ dis,
                       const float* __restrict__ xw, const float* __restrict__ bias,
                       float* __restrict__ xout) {
    int lane = threadIdx.x & 63;
    int warp = threadIdx.x >> 6;
    int nwarp = blockDim.x >> 6;
    int d = blockIdx.x * nwarp + warp;
    if (d >= NN) return;
    int beg = rp[d], end = rp[d + 1];
    float dd = dis[d];
    float acc = dd * xw[(size_t)d * H + lane];
    for (int b0 = beg; b0 < end; b0 += 64) {
        int n = end - b0;
        int sv = 0; float wv = 0.f;
        if (lane < n) {
            sv = csr_src[b0 + lane];
            wv = csr_w[b0 + lane];
        }
        int m = n < 64 ? n : 64;
        for (int j = 0; j < m; ++j) {
            int s = __shfl(sv, j);
            float w = __shfl(wv, j);
            acc += w * xw[(size_t)s * H + lane];
        }
    }
    xout[(size_t)d * H + lane] = fmaxf(dd * acc + bias[lane], 0.f);
}

// ---------------- per-node score y[i] = x[i]@lin_W + lin_b ----------------
__global__ void k_y(const float* __restrict__ x, const float* __restrict__ lw,
                    const float* __restrict__ lb, float* __restrict__ y) {
    int lane = threadIdx.x & 63;
    int warp = threadIdx.x >> 6;
    int nwarp = blockDim.x >> 6;
    int i = blockIdx.x * nwarp + warp;
    if (i >= NN) return;
    float v = x[(size_t)i * H + lane] * lw[lane];
    for (int off = 32; off > 0; off >>= 1) v += __shfl_down(v, off);
    if (lane == 0) y[i] = v + lb[0];
}

// ---------------- edge scoring: sigmoid(y[src]*y[dst]) ----------------
__global__ void k_out(const float* __restrict__ y, const int* __restrict__ ls,
                      const int* __restrict__ ld, float* __restrict__ out) {
    int e = blockIdx.x * blockDim.x + threadIdx.x;
    if (e < NL) {
        float z = y[ls[e]] * y[ld[e]];
        out[e] = 1.f / (1.f + __expf(-z));
    }
}

extern "C" void kernel_launch(void* const* d_in, const int* in_sizes, int n_in,
                              void* d_out, int out_size, void* d_ws, size_t ws_size,
                              hipStream_t stream) {
    const float* x_drug = (const float*)d_in[0];
    const float* x_prot = (const float*)d_in[1];
    const float* W_drug = (const float*)d_in[2];
    const float* b_drug = (const float*)d_in[3];
    const float* W_prot = (const float*)d_in[4];
    const float* b_prot = (const float*)d_in[5];
    const float* conv_W = (const float*)d_in[6];
    const float* conv_b = (const float*)d_in[7];
    const float* lin_W  = (const float*)d_in[8];
    const float* lin_b  = (const float*)d_in[9];
    const int*   ei     = (const int*)d_in[10];
    const int*   lsrc   = (const int*)d_in[11];
    const int*   ldst   = (const int*)d_in[12];
    float* out = (float*)d_out;

    char* w = (char*)d_ws;
    int*   cnt     = (int*)w;    w += (size_t)NN * 4;
    int*   rp      = (int*)w;    w += (size_t)(NN + 4) * 4;
    int*   cur     = (int*)w;    w += (size_t)NN * 4;
    int*   csr_src = (int*)w;    w += (size_t)NE * 4;
    float* csr_w   = (float*)w;  w += (size_t)NE * 4;
    float* dis     = (float*)w;  w += (size_t)NN * 4;
    float* xbuf    = (float*)w;  w += (size_t)NN * H * 4;
    float* xwbuf   = (float*)w;  w += (size_t)NN * H * 4;
    float* y       = (float*)w;  w += (size_t)NN * 4;

    hipMemsetAsync(cnt, 0, (size_t)NN * 4, stream);
    k_hist<<<(NE + 255) / 256, 256, 0, stream>>>(ei, cnt);
    k_dis<<<(NN + 255) / 256, 256, 0, stream>>>(cnt, dis);
    k_scan<<<1, SCAN_T, 0, stream>>>(cnt, rp, cur);
    k_scatter<<<(NE + 255) / 256, 256, 0, stream>>>(ei, dis, cur, csr_src, csr_w);

    k_gemm<F_DRUG, true><<<(N_DRUG + 127) / 128, 256, 0, stream>>>(
        x_drug, W_drug, b_drug, xbuf, N_DRUG, 0);
    k_gemm<F_PROT, true><<<(N_PROT + 127) / 128, 256, 0, stream>>>(
        x_prot, W_prot, b_prot, xbuf, N_PROT, N_DRUG);

    for (int l = 0; l < LAYERS; ++l) {
        k_gemm<H, false><<<(NN + 127) / 128, 256, 0, stream>>>(
            xbuf, conv_W + (size_t)l * H * H, nullptr, xwbuf, NN, 0);
        k_spmm<<<(NN + 3) / 4, 256, 0, stream>>>(rp, csr_src, csr_w, dis, xwbuf,
                                                 conv_b + (size_t)l * H, xbuf);
    }

    k_y<<<(NN + 3) / 4, 256, 0, stream>>>(xbuf, lin_W, lin_b, y);
    k_out<<<(NL + 255) / 256, 256, 0, stream>>>(y, lsrc, ldst, out);
}

// Round 3
// 654.351 us; speedup vs baseline: 2.1246x; 1.1665x over previous
//
#include <hip/hip_runtime.h>
#include <math.h>

#define N_DRUG 20000
#define N_PROT 30000
#define NN (N_DRUG + N_PROT)
#define F_DRUG 128
#define F_PROT 256
#define H 64
#define NE 1600000
#define NL 200000
#define LAYERS 3

#define NB_PROJD ((N_DRUG + 127) / 128)          // 157
#define NB_PROJP ((N_PROT + 127) / 128)          // 235
#define NB_HIST  ((NE / 4 + 255) / 256)          // 1563
#define NB_CONV  ((NN + 127) / 128)              // 391

// ---------------- register-blocked tiled GEMM (256 threads, 128x64 tile) ----------------
// thread: 8 rows x 4 cols accumulator. K staged in 64-chunks.
__device__ __forceinline__ void gemm_tile(
    const float* __restrict__ X, const float* __restrict__ W,
    const float* __restrict__ bias, float* __restrict__ out,
    int rows, int row_off, int F, bool relu,
    float (*Xs)[65], float (*Ws)[64], int bid) {
    int tid = threadIdx.x;
    int r0 = bid * 128;
    int rg = tid >> 4;        // 0..15
    int cg = tid & 15;        // 0..15
    float acc[8][4];
    #pragma unroll
    for (int i = 0; i < 8; ++i)
        #pragma unroll
        for (int j = 0; j < 4; ++j) acc[i][j] = 0.f;

    for (int k0 = 0; k0 < F; k0 += 64) {
        #pragma unroll
        for (int idx = tid; idx < 128 * 64; idx += 256) {
            int r = idx >> 6, f = idx & 63;
            int gr = r0 + r;
            Xs[r][f] = (gr < rows) ? X[(size_t)gr * F + k0 + f] : 0.f;
        }
        #pragma unroll
        for (int idx = tid; idx < 64 * 64; idx += 256) {
            int k = idx >> 6, c = idx & 63;
            Ws[k][c] = W[(size_t)(k0 + k) * H + c];
        }
        __syncthreads();
        #pragma unroll 4
        for (int k = 0; k < 64; ++k) {
            float a[8];
            #pragma unroll
            for (int i = 0; i < 8; ++i) a[i] = Xs[rg * 8 + i][k];
            float4 bb = *(const float4*)&Ws[k][cg * 4];
            #pragma unroll
            for (int i = 0; i < 8; ++i) {
                acc[i][0] += a[i] * bb.x;
                acc[i][1] += a[i] * bb.y;
                acc[i][2] += a[i] * bb.z;
                acc[i][3] += a[i] * bb.w;
            }
        }
        __syncthreads();
    }
    float4 bv = make_float4(0.f, 0.f, 0.f, 0.f);
    if (bias) bv = *(const float4*)&bias[cg * 4];
    #pragma unroll
    for (int i = 0; i < 8; ++i) {
        int gr = r0 + rg * 8 + i;
        if (gr < rows) {
            float4 v;
            v.x = acc[i][0] + bv.x;
            v.y = acc[i][1] + bv.y;
            v.z = acc[i][2] + bv.z;
            v.w = acc[i][3] + bv.w;
            if (relu) {
                v.x = fmaxf(v.x, 0.f); v.y = fmaxf(v.y, 0.f);
                v.z = fmaxf(v.z, 0.f); v.w = fmaxf(v.w, 0.f);
            }
            *(float4*)&out[(size_t)(row_off + gr) * H + cg * 4] = v;
        }
    }
}

// ---------------- fused front: proj_drug || proj_prot || degree histogram ----------------
__global__ __launch_bounds__(256) void k_front(
    const float* __restrict__ xd, const float* __restrict__ Wd, const float* __restrict__ bd,
    const float* __restrict__ xp, const float* __restrict__ Wp, const float* __restrict__ bp,
    const int* __restrict__ ei, int* __restrict__ cnt, float* __restrict__ xbuf) {
    __shared__ float Xs[128][65];
    __shared__ float Ws[64][64];
    int bid = blockIdx.x;
    if (bid < NB_PROJD) {
        gemm_tile(xd, Wd, bd, xbuf, N_DRUG, 0, F_DRUG, true, Xs, Ws, bid);
    } else if (bid < NB_PROJD + NB_PROJP) {
        gemm_tile(xp, Wp, bp, xbuf, N_PROT, N_DRUG, F_PROT, true, Xs, Ws, bid - NB_PROJD);
    } else {
        int idx = (bid - NB_PROJD - NB_PROJP) * 256 + threadIdx.x;
        int e = idx * 4;
        if (e < NE) {
            int4 d4 = *(const int4*)&ei[NE + e];
            atomicAdd(&cnt[d4.x], 1); atomicAdd(&cnt[d4.y], 1);
            atomicAdd(&cnt[d4.z], 1); atomicAdd(&cnt[d4.w], 1);
        }
    }
}

// ---------------- fused mid: scan(+dis) on block 0 || conv GEMM layer 0 ----------------
#define SCAN_T 256
__global__ __launch_bounds__(256) void k_mid(
    const int* __restrict__ cnt, int* __restrict__ rp, int* __restrict__ cur,
    float* __restrict__ dis, const float* __restrict__ xbuf,
    const float* __restrict__ convW0, float* __restrict__ xwbuf) {
    __shared__ float Xs[128][65];
    __shared__ float Ws[64][64];
    __shared__ int sums[SCAN_T];
    int bid = blockIdx.x;
    if (bid == 0) {
        int t = threadIdx.x;
        const int chunk = (NN + SCAN_T - 1) / SCAN_T;   // 196
        int lo = t * chunk;
        int hi = lo + chunk; if (hi > NN) hi = NN;
        int s = 0;
        for (int i = lo; i < hi; ++i) s += cnt[i];
        sums[t] = s;
        __syncthreads();
        for (int off = 1; off < SCAN_T; off <<= 1) {
            int v = sums[t];
            int u = (t >= off) ? sums[t - off] : 0;
            __syncthreads();
            sums[t] = v + u;
            __syncthreads();
        }
        int run = (t > 0) ? sums[t - 1] : 0;
        for (int i = lo; i < hi; ++i) {
            int c = cnt[i];
            rp[i] = run; cur[i] = run;
            dis[i] = rsqrtf((float)c + 1.0f);
            run += c;
        }
        if (t == SCAN_T - 1) rp[NN] = run;
    } else {
        gemm_tile(xbuf, convW0, nullptr, xwbuf, NN, 0, H, false, Xs, Ws, bid - 1);
    }
}

// ---------------- standalone conv GEMM for layers 1,2 ----------------
__global__ __launch_bounds__(256) void k_conv(
    const float* __restrict__ X, const float* __restrict__ W, float* __restrict__ out) {
    __shared__ float Xs[128][65];
    __shared__ float Ws[64][64];
    gemm_tile(X, W, nullptr, out, NN, 0, H, false, Xs, Ws, blockIdx.x);
}

// ---------------- scatter edges into CSR (src only, 4 edges/thread) ----------------
__global__ void k_scatter(const int* __restrict__ ei, int* __restrict__ cur,
                          int* __restrict__ csr_src) {
    int idx = blockIdx.x * blockDim.x + threadIdx.x;
    int e = idx * 4;
    if (e < NE) {
        int4 s4 = *(const int4*)&ei[e];
        int4 d4 = *(const int4*)&ei[NE + e];
        int p0 = atomicAdd(&cur[d4.x], 1); csr_src[p0] = s4.x;
        int p1 = atomicAdd(&cur[d4.y], 1); csr_src[p1] = s4.y;
        int p2 = atomicAdd(&cur[d4.z], 1); csr_src[p2] = s4.z;
        int p3 = atomicAdd(&cur[d4.w], 1); csr_src[p3] = s4.w;
    }
}

// ---------------- SpMM + self-term + bias + relu; LAST fuses y = x@lin_W + lin_b ----------------
template <bool LAST>
__global__ __launch_bounds__(256) void k_spmm(
    const int* __restrict__ rp, const int* __restrict__ csr_src,
    const float* __restrict__ dis, const float* __restrict__ xw,
    const float* __restrict__ bias, float* __restrict__ xout,
    const float* __restrict__ lw, const float* __restrict__ lb,
    float* __restrict__ y) {
    int lane = threadIdx.x & 63;
    int warp = threadIdx.x >> 6;
    int d = blockIdx.x * 4 + warp;
    if (d >= NN) return;
    int beg = rp[d], end = rp[d + 1];
    float dd = dis[d];
    float acc0 = dd * xw[(size_t)d * H + lane];
    float acc1 = 0.f;
    int n = end - beg; if (n > 64) n = 64;
    int sv = 0; float wv = 0.f;
    if (lane < n) { sv = csr_src[beg + lane]; wv = dis[sv]; }
    for (int b0 = beg; b0 < end; ) {
        int nb = b0 + 64;
        int n2 = end - nb; if (n2 > 64) n2 = 64;
        int sv2 = 0; float wv2 = 0.f;
        if (n2 > 0 && lane < n2) { sv2 = csr_src[nb + lane]; wv2 = dis[sv2]; }
        int j = 0;
        for (; j + 1 < n; j += 2) {
            int s0 = __shfl(sv, j);     float w0 = __shfl(wv, j);
            int s1 = __shfl(sv, j + 1); float w1 = __shfl(wv, j + 1);
            acc0 += w0 * xw[(size_t)s0 * H + lane];
            acc1 += w1 * xw[(size_t)s1 * H + lane];
        }
        if (j < n) {
            int s0 = __shfl(sv, j); float w0 = __shfl(wv, j);
            acc0 += w0 * xw[(size_t)s0 * H + lane];
        }
        b0 = nb; n = n2; sv = sv2; wv = wv2;
    }
    float v = fmaxf(dd * (acc0 + acc1) + bias[lane], 0.f);
    if (LAST) {
        float t = v * lw[lane];
        #pragma unroll
        for (int off = 32; off; off >>= 1) t += __shfl_xor(t, off);
        if (lane == 0) y[d] = t + lb[0];
    } else {
        xout[(size_t)d * H + lane] = v;
    }
}

// ---------------- edge scoring: sigmoid(y[src]*y[dst]) ----------------
__global__ void k_out(const float* __restrict__ y, const int* __restrict__ ls,
                      const int* __restrict__ ld, float* __restrict__ out) {
    int e = blockIdx.x * blockDim.x + threadIdx.x;
    if (e < NL) {
        float z = y[ls[e]] * y[ld[e]];
        out[e] = 1.f / (1.f + __expf(-z));
    }
}

extern "C" void kernel_launch(void* const* d_in, const int* in_sizes, int n_in,
                              void* d_out, int out_size, void* d_ws, size_t ws_size,
                              hipStream_t stream) {
    const float* x_drug = (const float*)d_in[0];
    const float* x_prot = (const float*)d_in[1];
    const float* W_drug = (const float*)d_in[2];
    const float* b_drug = (const float*)d_in[3];
    const float* W_prot = (const float*)d_in[4];
    const float* b_prot = (const float*)d_in[5];
    const float* conv_W = (const float*)d_in[6];
    const float* conv_b = (const float*)d_in[7];
    const float* lin_W  = (const float*)d_in[8];
    const float* lin_b  = (const float*)d_in[9];
    const int*   ei     = (const int*)d_in[10];
    const int*   lsrc   = (const int*)d_in[11];
    const int*   ldst   = (const int*)d_in[12];
    float* out = (float*)d_out;

    char* w = (char*)d_ws;
    int*   cnt     = (int*)w;    w += (size_t)NN * 4;
    int*   rp      = (int*)w;    w += (size_t)(NN + 4) * 4;
    int*   cur     = (int*)w;    w += (size_t)NN * 4;
    int*   csr_src = (int*)w;    w += (size_t)NE * 4;
    float* dis     = (float*)w;  w += (size_t)NN * 4;
    float* xbuf    = (float*)w;  w += (size_t)NN * H * 4;
    float* xwbuf   = (float*)w;  w += (size_t)NN * H * 4;
    float* y       = (float*)w;  w += (size_t)NN * 4;

    hipMemsetAsync(cnt, 0, (size_t)NN * 4, stream);

    // proj_drug || proj_prot || hist
    k_front<<<NB_PROJD + NB_PROJP + NB_HIST, 256, 0, stream>>>(
        x_drug, W_drug, b_drug, x_prot, W_prot, b_prot, ei, cnt, xbuf);

    // scan(+dis) || conv GEMM layer 0
    k_mid<<<1 + NB_CONV, 256, 0, stream>>>(cnt, rp, cur, dis, xbuf, conv_W, xwbuf);

    k_scatter<<<(NE / 4 + 255) / 256, 256, 0, stream>>>(ei, cur, csr_src);

    // layer 0
    k_spmm<false><<<(NN + 3) / 4, 256, 0, stream>>>(
        rp, csr_src, dis, xwbuf, conv_b, xbuf, nullptr, nullptr, nullptr);
    // layer 1
    k_conv<<<NB_CONV, 256, 0, stream>>>(xbuf, conv_W + (size_t)1 * H * H, xwbuf);
    k_spmm<false><<<(NN + 3) / 4, 256, 0, stream>>>(
        rp, csr_src, dis, xwbuf, conv_b + H, xbuf, nullptr, nullptr, nullptr);
    // layer 2 (fused y epilogue, no x3 write)
    k_conv<<<NB_CONV, 256, 0, stream>>>(xbuf, conv_W + (size_t)2 * H * H, xwbuf);
    k_spmm<true><<<(NN + 3) / 4, 256, 0, stream>>>(
        rp, csr_src, dis, xwbuf, conv_b + 2 * H, nullptr, lin_W, lin_b, y);

    k_out<<<(NL + 255) / 256, 256, 0, stream>>>(y, lsrc, ldst, out);
}

// Round 4
// 453.288 us; speedup vs baseline: 3.0671x; 1.4436x over previous
//
#include <hip/hip_runtime.h>
#include <hip/hip_fp16.h>
#include <math.h>

#define N_DRUG 20000
#define N_PROT 30000
#define NN (N_DRUG + N_PROT)
#define F_DRUG 128
#define F_PROT 256
#define H 64
#define NE 1600000
#define NL 200000

#define NB_PROJD ((N_DRUG + 127) / 128)          // 157
#define NB_PROJP ((N_PROT + 127) / 128)          // 235
#define NB_HIST  ((NE / 4 + 255) / 256)          // 1563
#define NB_CONV  ((NN + 127) / 128)              // 391
#define NB_RED   ((NN + 255) / 256)              // 196

// ---------------- register-blocked tiled GEMM (256 threads, 128x64 tile) ----------------
// thread: 8 rows x 4 cols accumulator. K staged in 64-chunks.
// HOUT: write output as __half (fp32 accumulate, round once).
template <bool RELU, bool HOUT>
__device__ __forceinline__ void gemm_tile(
    const float* __restrict__ X, const float* __restrict__ W,
    const float* __restrict__ bias, void* __restrict__ outp,
    int rows, int row_off, int F,
    float (*Xs)[65], float (*Ws)[64], int bid) {
    int tid = threadIdx.x;
    int r0 = bid * 128;
    int rg = tid >> 4;        // 0..15
    int cg = tid & 15;        // 0..15
    float acc[8][4];
    #pragma unroll
    for (int i = 0; i < 8; ++i)
        #pragma unroll
        for (int j = 0; j < 4; ++j) acc[i][j] = 0.f;

    for (int k0 = 0; k0 < F; k0 += 64) {
        #pragma unroll
        for (int idx = tid; idx < 128 * 64; idx += 256) {
            int r = idx >> 6, f = idx & 63;
            int gr = r0 + r;
            Xs[r][f] = (gr < rows) ? X[(size_t)gr * F + k0 + f] : 0.f;
        }
        #pragma unroll
        for (int idx = tid; idx < 64 * 64; idx += 256) {
            int k = idx >> 6, c = idx & 63;
            Ws[k][c] = W[(size_t)(k0 + k) * H + c];
        }
        __syncthreads();
        #pragma unroll 4
        for (int k = 0; k < 64; ++k) {
            float a[8];
            #pragma unroll
            for (int i = 0; i < 8; ++i) a[i] = Xs[rg * 8 + i][k];
            float4 bb = *(const float4*)&Ws[k][cg * 4];
            #pragma unroll
            for (int i = 0; i < 8; ++i) {
                acc[i][0] += a[i] * bb.x;
                acc[i][1] += a[i] * bb.y;
                acc[i][2] += a[i] * bb.z;
                acc[i][3] += a[i] * bb.w;
            }
        }
        __syncthreads();
    }
    float4 bv = make_float4(0.f, 0.f, 0.f, 0.f);
    if (bias) bv = *(const float4*)&bias[cg * 4];
    #pragma unroll
    for (int i = 0; i < 8; ++i) {
        int gr = r0 + rg * 8 + i;
        if (gr < rows) {
            float4 v;
            v.x = acc[i][0] + bv.x;
            v.y = acc[i][1] + bv.y;
            v.z = acc[i][2] + bv.z;
            v.w = acc[i][3] + bv.w;
            if (RELU) {
                v.x = fmaxf(v.x, 0.f); v.y = fmaxf(v.y, 0.f);
                v.z = fmaxf(v.z, 0.f); v.w = fmaxf(v.w, 0.f);
            }
            size_t col = (size_t)(row_off + gr) * H + cg * 4;
            if (HOUT) {
                __half2 hh[2];
                hh[0] = __floats2half2_rn(v.x, v.y);
                hh[1] = __floats2half2_rn(v.z, v.w);
                *(uint2*)((__half*)outp + col) = *(uint2*)hh;
            } else {
                *(float4*)((float*)outp + col) = v;
            }
        }
    }
}

// ---------------- fused front: proj_drug || proj_prot || degree histogram ----------------
__global__ __launch_bounds__(256) void k_front(
    const float* __restrict__ xd, const float* __restrict__ Wd, const float* __restrict__ bd,
    const float* __restrict__ xp, const float* __restrict__ Wp, const float* __restrict__ bp,
    const int* __restrict__ ei, int* __restrict__ cnt, float* __restrict__ xbuf) {
    __shared__ float Xs[128][65];
    __shared__ float Ws[64][64];
    int bid = blockIdx.x;
    if (bid < NB_PROJD) {
        gemm_tile<true, false>(xd, Wd, bd, xbuf, N_DRUG, 0, F_DRUG, Xs, Ws, bid);
    } else if (bid < NB_PROJD + NB_PROJP) {
        gemm_tile<true, false>(xp, Wp, bp, xbuf, N_PROT, N_DRUG, F_PROT, Xs, Ws, bid - NB_PROJD);
    } else {
        int idx = (bid - NB_PROJD - NB_PROJP) * 256 + threadIdx.x;
        int e = idx * 4;
        if (e < NE) {
            int4 d4 = *(const int4*)&ei[NE + e];
            atomicAdd(&cnt[d4.x], 1); atomicAdd(&cnt[d4.y], 1);
            atomicAdd(&cnt[d4.z], 1); atomicAdd(&cnt[d4.w], 1);
        }
    }
}

// ---------------- fused: per-block degree reduce || conv GEMM layer 0 (half out) ----------------
__global__ __launch_bounds__(256) void k_redconv(
    const int* __restrict__ cnt, int* __restrict__ bsum,
    const float* __restrict__ xbuf, const float* __restrict__ W0,
    __half* __restrict__ xwh) {
    __shared__ float Xs[128][65];
    __shared__ float Ws[64][64];
    __shared__ int wsum[4];
    int bid = blockIdx.x;
    if (bid < NB_RED) {
        int i = bid * 256 + threadIdx.x;
        int v = (i < NN) ? cnt[i] : 0;
        #pragma unroll
        for (int off = 32; off; off >>= 1) v += __shfl_xor(v, off);
        int lane = threadIdx.x & 63, wid = threadIdx.x >> 6;
        if (lane == 0) wsum[wid] = v;
        __syncthreads();
        if (threadIdx.x == 0) bsum[bid] = wsum[0] + wsum[1] + wsum[2] + wsum[3];
    } else {
        gemm_tile<false, true>(xbuf, W0, nullptr, xwh, NN, 0, H, Xs, Ws, bid - NB_RED);
    }
}

// ---------------- hierarchical scan phase B: rp/cur/dis, fully parallel ----------------
__global__ __launch_bounds__(256) void k_scanB(
    const int* __restrict__ cnt, const int* __restrict__ bsum,
    int* __restrict__ rp, int* __restrict__ cur, float* __restrict__ dis) {
    __shared__ int sb[256], sl[256];
    int t = threadIdx.x, b = blockIdx.x;
    sb[t] = (t < NB_RED) ? bsum[t] : 0;
    __syncthreads();
    for (int off = 1; off < 256; off <<= 1) {
        int v = sb[t]; int u = (t >= off) ? sb[t - off] : 0;
        __syncthreads(); sb[t] = v + u; __syncthreads();
    }
    int P = (b > 0) ? sb[b - 1] : 0;
    int i = b * 256 + t;
    int c = (i < NN) ? cnt[i] : 0;
    sl[t] = c;
    __syncthreads();
    for (int off = 1; off < 256; off <<= 1) {
        int v = sl[t]; int u = (t >= off) ? sl[t - off] : 0;
        __syncthreads(); sl[t] = v + u; __syncthreads();
    }
    if (i < NN) {
        int r = P + sl[t] - c;
        rp[i] = r; cur[i] = r;
        dis[i] = rsqrtf((float)c + 1.0f);
    }
    if (b == 0 && t == 0) rp[NN] = NE;
}

// ---------------- standalone conv GEMM for layers 1,2 (half out) ----------------
__global__ __launch_bounds__(256) void k_conv(
    const float* __restrict__ X, const float* __restrict__ W, __half* __restrict__ out) {
    __shared__ float Xs[128][65];
    __shared__ float Ws[64][64];
    gemm_tile<false, true>(X, W, nullptr, out, NN, 0, H, Xs, Ws, blockIdx.x);
}

// ---------------- scatter edges into CSR (src only, 4 edges/thread) ----------------
__global__ void k_scatter(const int* __restrict__ ei, int* __restrict__ cur,
                          int* __restrict__ csr_src) {
    int idx = blockIdx.x * blockDim.x + threadIdx.x;
    int e = idx * 4;
    if (e < NE) {
        int4 s4 = *(const int4*)&ei[e];
        int4 d4 = *(const int4*)&ei[NE + e];
        int p0 = atomicAdd(&cur[d4.x], 1); csr_src[p0] = s4.x;
        int p1 = atomicAdd(&cur[d4.y], 1); csr_src[p1] = s4.y;
        int p2 = atomicAdd(&cur[d4.z], 1); csr_src[p2] = s4.z;
        int p3 = atomicAdd(&cur[d4.w], 1); csr_src[p3] = s4.w;
    }
}

// ---------------- SpMM + self-term + bias + relu; LAST fuses y = x@lin_W + lin_b ----------------
template <bool LAST>
__global__ __launch_bounds__(256) void k_spmm(
    const int* __restrict__ rp, const int* __restrict__ csr_src,
    const float* __restrict__ dis, const __half* __restrict__ xw,
    const float* __restrict__ bias, float* __restrict__ xout,
    const float* __restrict__ lw, const float* __restrict__ lb,
    float* __restrict__ y) {
    int lane = threadIdx.x & 63;
    int warp = threadIdx.x >> 6;
    int d = blockIdx.x * 4 + warp;
    if (d >= NN) return;
    int beg = rp[d], end = rp[d + 1];
    float dd = dis[d];
    float acc0 = dd * __half2float(xw[(size_t)d * H + lane]);
    float acc1 = 0.f, acc2 = 0.f, acc3 = 0.f;
    int n = end - beg; if (n > 64) n = 64;
    int sv = 0; float wv = 0.f;
    if (lane < n) { sv = csr_src[beg + lane]; wv = dis[sv]; }
    for (int b0 = beg; b0 < end; ) {
        int nb = b0 + 64;
        int n2 = end - nb; if (n2 > 64) n2 = 64;
        int sv2 = 0; float wv2 = 0.f;
        if (n2 > 0 && lane < n2) { sv2 = csr_src[nb + lane]; wv2 = dis[sv2]; }
        int j = 0;
        for (; j + 3 < n; j += 4) {
            int s0 = __shfl(sv, j);     float w0 = __shfl(wv, j);
            int s1 = __shfl(sv, j + 1); float w1 = __shfl(wv, j + 1);
            int s2 = __shfl(sv, j + 2); float w2 = __shfl(wv, j + 2);
            int s3 = __shfl(sv, j + 3); float w3 = __shfl(wv, j + 3);
            acc0 += w0 * __half2float(xw[(size_t)s0 * H + lane]);
            acc1 += w1 * __half2float(xw[(size_t)s1 * H + lane]);
            acc2 += w2 * __half2float(xw[(size_t)s2 * H + lane]);
            acc3 += w3 * __half2float(xw[(size_t)s3 * H + lane]);
        }
        for (; j < n; ++j) {
            int s0 = __shfl(sv, j); float w0 = __shfl(wv, j);
            acc0 += w0 * __half2float(xw[(size_t)s0 * H + lane]);
        }
        b0 = nb; n = n2; sv = sv2; wv = wv2;
    }
    float v = fmaxf(dd * ((acc0 + acc1) + (acc2 + acc3)) + bias[lane], 0.f);
    if (LAST) {
        float t = v * lw[lane];
        #pragma unroll
        for (int off = 32; off; off >>= 1) t += __shfl_xor(t, off);
        if (lane == 0) y[d] = t + lb[0];
    } else {
        xout[(size_t)d * H + lane] = v;
    }
}

// ---------------- edge scoring: sigmoid(y[src]*y[dst]) ----------------
__global__ void k_out(const float* __restrict__ y, const int* __restrict__ ls,
                      const int* __restrict__ ld, float* __restrict__ out) {
    int e = blockIdx.x * blockDim.x + threadIdx.x;
    if (e < NL) {
        float z = y[ls[e]] * y[ld[e]];
        out[e] = 1.f / (1.f + __expf(-z));
    }
}

extern "C" void kernel_launch(void* const* d_in, const int* in_sizes, int n_in,
                              void* d_out, int out_size, void* d_ws, size_t ws_size,
                              hipStream_t stream) {
    const float* x_drug = (const float*)d_in[0];
    const float* x_prot = (const float*)d_in[1];
    const float* W_drug = (const float*)d_in[2];
    const float* b_drug = (const float*)d_in[3];
    const float* W_prot = (const float*)d_in[4];
    const float* b_prot = (const float*)d_in[5];
    const float* conv_W = (const float*)d_in[6];
    const float* conv_b = (const float*)d_in[7];
    const float* lin_W  = (const float*)d_in[8];
    const float* lin_b  = (const float*)d_in[9];
    const int*   ei     = (const int*)d_in[10];
    const int*   lsrc   = (const int*)d_in[11];
    const int*   ldst   = (const int*)d_in[12];
    float* out = (float*)d_out;

    char* w = (char*)d_ws;
    int*    cnt     = (int*)w;     w += (size_t)NN * 4;
    int*    rp      = (int*)w;     w += (size_t)(NN + 4) * 4;
    int*    cur     = (int*)w;     w += (size_t)NN * 4;
    int*    bsum    = (int*)w;     w += 256 * 4;
    int*    csr_src = (int*)w;     w += (size_t)NE * 4;
    float*  dis     = (float*)w;   w += (size_t)NN * 4;
    float*  xbuf    = (float*)w;   w += (size_t)NN * H * 4;
    __half* xwh     = (__half*)w;  w += (size_t)NN * H * 2;
    float*  y       = (float*)w;   w += (size_t)NN * 4;

    hipMemsetAsync(cnt, 0, (size_t)NN * 4, stream);

    // proj_drug || proj_prot || hist
    k_front<<<NB_PROJD + NB_PROJP + NB_HIST, 256, 0, stream>>>(
        x_drug, W_drug, b_drug, x_prot, W_prot, b_prot, ei, cnt, xbuf);

    // per-block degree reduce || conv GEMM layer 0
    k_redconv<<<NB_RED + NB_CONV, 256, 0, stream>>>(cnt, bsum, xbuf, conv_W, xwh);
    k_scanB<<<NB_RED, 256, 0, stream>>>(cnt, bsum, rp, cur, dis);
    k_scatter<<<(NE / 4 + 255) / 256, 256, 0, stream>>>(ei, cur, csr_src);

    // layer 0
    k_spmm<false><<<(NN + 3) / 4, 256, 0, stream>>>(
        rp, csr_src, dis, xwh, conv_b, xbuf, nullptr, nullptr, nullptr);
    // layer 1
    k_conv<<<NB_CONV, 256, 0, stream>>>(xbuf, conv_W + (size_t)1 * H * H, xwh);
    k_spmm<false><<<(NN + 3) / 4, 256, 0, stream>>>(
        rp, csr_src, dis, xwh, conv_b + H, xbuf, nullptr, nullptr, nullptr);
    // layer 2 (fused y epilogue, no x3 write)
    k_conv<<<NB_CONV, 256, 0, stream>>>(xbuf, conv_W + (size_t)2 * H * H, xwh);
    k_spmm<true><<<(NN + 3) / 4, 256, 0, stream>>>(
        rp, csr_src, dis, xwh, conv_b + 2 * H, nullptr, lin_W, lin_b, y);

    k_out<<<(NL + 255) / 256, 256, 0, stream>>>(y, lsrc, ldst, out);
}

// Round 5
// 295.581 us; speedup vs baseline: 4.7035x; 1.5335x over previous
//
#include <hip/hip_runtime.h>
#include <hip/hip_fp16.h>
#include <math.h>

#define N_DRUG 20000
#define N_PROT 30000
#define NN (N_DRUG + N_PROT)
#define F_DRUG 128
#define F_PROT 256
#define H 64
#define NE 1600000
#define NL 200000

#define NB_PROJD ((N_DRUG + 127) / 128)          // 157
#define NB_PROJP ((N_PROT + 127) / 128)          // 235
#define NB_CONV  ((NN + 127) / 128)              // 391
#define NBK1 256                                  // partition blocks
#define CH   ((NE + NBK1 - 1) / NBK1)            // 6250 edges/block
#define NB_BKT ((NN + 255) / 256)                // 196 buckets in use

// ---------------- register-blocked tiled GEMM (256 threads, 128x64 tile) ----------------
template <bool RELU, bool HOUT>
__device__ __forceinline__ void gemm_tile(
    const float* __restrict__ X, const float* __restrict__ W,
    const float* __restrict__ bias, void* __restrict__ outp,
    int rows, int row_off, int F,
    float (*Xs)[65], float (*Ws)[64], int bid) {
    int tid = threadIdx.x;
    int r0 = bid * 128;
    int rg = tid >> 4;
    int cg = tid & 15;
    float acc[8][4];
    #pragma unroll
    for (int i = 0; i < 8; ++i)
        #pragma unroll
        for (int j = 0; j < 4; ++j) acc[i][j] = 0.f;

    for (int k0 = 0; k0 < F; k0 += 64) {
        #pragma unroll
        for (int idx = tid; idx < 128 * 64; idx += 256) {
            int r = idx >> 6, f = idx & 63;
            int gr = r0 + r;
            Xs[r][f] = (gr < rows) ? X[(size_t)gr * F + k0 + f] : 0.f;
        }
        #pragma unroll
        for (int idx = tid; idx < 64 * 64; idx += 256) {
            int k = idx >> 6, c = idx & 63;
            Ws[k][c] = W[(size_t)(k0 + k) * H + c];
        }
        __syncthreads();
        #pragma unroll 4
        for (int k = 0; k < 64; ++k) {
            float a[8];
            #pragma unroll
            for (int i = 0; i < 8; ++i) a[i] = Xs[rg * 8 + i][k];
            float4 bb = *(const float4*)&Ws[k][cg * 4];
            #pragma unroll
            for (int i = 0; i < 8; ++i) {
                acc[i][0] += a[i] * bb.x;
                acc[i][1] += a[i] * bb.y;
                acc[i][2] += a[i] * bb.z;
                acc[i][3] += a[i] * bb.w;
            }
        }
        __syncthreads();
    }
    float4 bv = make_float4(0.f, 0.f, 0.f, 0.f);
    if (bias) bv = *(const float4*)&bias[cg * 4];
    #pragma unroll
    for (int i = 0; i < 8; ++i) {
        int gr = r0 + rg * 8 + i;
        if (gr < rows) {
            float4 v;
            v.x = acc[i][0] + bv.x;
            v.y = acc[i][1] + bv.y;
            v.z = acc[i][2] + bv.z;
            v.w = acc[i][3] + bv.w;
            if (RELU) {
                v.x = fmaxf(v.x, 0.f); v.y = fmaxf(v.y, 0.f);
                v.z = fmaxf(v.z, 0.f); v.w = fmaxf(v.w, 0.f);
            }
            size_t col = (size_t)(row_off + gr) * H + cg * 4;
            if (HOUT) {
                __half2 hh[2];
                hh[0] = __floats2half2_rn(v.x, v.y);
                hh[1] = __floats2half2_rn(v.z, v.w);
                *(uint2*)((__half*)outp + col) = *(uint2*)hh;
            } else {
                *(float4*)((float*)outp + col) = v;
            }
        }
    }
}

// ---------------- fused front: proj_drug || proj_prot || coarse bucket hist (LDS) ----------------
__global__ __launch_bounds__(256) void k_front(
    const float* __restrict__ xd, const float* __restrict__ Wd, const float* __restrict__ bd,
    const float* __restrict__ xp, const float* __restrict__ Wp, const float* __restrict__ bp,
    const int* __restrict__ ei, unsigned* __restrict__ bhist, float* __restrict__ xbuf) {
    __shared__ float Xs[128][65];
    __shared__ float Ws[64][64];
    __shared__ unsigned lh[256];
    int bid = blockIdx.x;
    if (bid < NB_PROJD) {
        gemm_tile<true, false>(xd, Wd, bd, xbuf, N_DRUG, 0, F_DRUG, Xs, Ws, bid);
    } else if (bid < NB_PROJD + NB_PROJP) {
        gemm_tile<true, false>(xp, Wp, bp, xbuf, N_PROT, N_DRUG, F_PROT, Xs, Ws, bid - NB_PROJD);
    } else {
        int blk = bid - NB_PROJD - NB_PROJP;   // 0..NBK1-1
        int t = threadIdx.x;
        lh[t] = 0;
        __syncthreads();
        int eb = blk * CH, ee = min(NE, eb + CH);
        for (int e = eb + t; e < ee; e += 256)
            atomicAdd(&lh[((unsigned)ei[NE + e]) >> 8], 1u);
        __syncthreads();
        bhist[(size_t)t * NBK1 + blk] = lh[t];   // bucket-major
    }
}

// ---------------- scan step A: per-bucket row sums ----------------
__global__ __launch_bounds__(256) void kA(const unsigned* __restrict__ bhist,
                                          unsigned* __restrict__ rsum) {
    __shared__ unsigned s[256];
    int j = blockIdx.x, t = threadIdx.x;
    s[t] = bhist[(size_t)j * NBK1 + t];
    __syncthreads();
    for (int off = 128; off; off >>= 1) {
        if (t < off) s[t] += s[t + off];
        __syncthreads();
    }
    if (t == 0) rsum[j] = s[0];
}

// ---------------- scan step B: exclusive scan of bucket totals ----------------
__global__ __launch_bounds__(256) void kB(const unsigned* __restrict__ rsum,
                                          unsigned* __restrict__ rbase) {
    __shared__ unsigned s[256];
    int t = threadIdx.x;
    unsigned c = rsum[t];
    s[t] = c;
    __syncthreads();
    for (int off = 1; off < 256; off <<= 1) {
        unsigned v = s[t]; unsigned u = (t >= off) ? s[t - off] : 0;
        __syncthreads(); s[t] = v + u; __syncthreads();
    }
    rbase[t] = s[t] - c;
    if (t == 255) rbase[256] = s[255];   // == NE
}

// ---------------- scan step C: per-bucket row exclusive scan + offset ----------------
__global__ __launch_bounds__(256) void kC(unsigned* __restrict__ bhist,
                                          const unsigned* __restrict__ rbase) {
    __shared__ unsigned s[256];
    int j = blockIdx.x, t = threadIdx.x;
    unsigned c = bhist[(size_t)j * NBK1 + t];
    s[t] = c;
    __syncthreads();
    for (int off = 1; off < 256; off <<= 1) {
        unsigned v = s[t]; unsigned u = (t >= off) ? s[t - off] : 0;
        __syncthreads(); s[t] = v + u; __syncthreads();
    }
    bhist[(size_t)j * NBK1 + t] = rbase[j] + s[t] - c;
}

// ---------------- fused: bucket partition-scatter (LDS cursors) || conv GEMM layer 0 ----------------
__global__ __launch_bounds__(256) void k_part(
    const int* __restrict__ ei, const unsigned* __restrict__ base,
    unsigned* __restrict__ tmp,
    const float* __restrict__ xbuf, const float* __restrict__ W0,
    __half* __restrict__ xwh) {
    __shared__ float Xs[128][65];
    __shared__ float Ws[64][64];
    __shared__ unsigned lcur[256];
    int bid = blockIdx.x;
    if (bid < NBK1) {
        int t = threadIdx.x;
        lcur[t] = base[(size_t)t * NBK1 + bid];
        __syncthreads();
        int eb = bid * CH, ee = min(NE, eb + CH);
        for (int e = eb + t; e < ee; e += 256) {
            unsigned s = (unsigned)ei[e];
            unsigned d = (unsigned)ei[NE + e];
            unsigned pos = atomicAdd(&lcur[d >> 8], 1u);
            tmp[pos] = ((d & 255u) << 16) | s;
        }
    } else {
        gemm_tile<false, true>(xbuf, W0, nullptr, xwh, NN, 0, H, Xs, Ws, bid - NBK1);
    }
}

// ---------------- per-bucket CSR finalize: rp, dis, csr_src(u16). No global atomics ----------------
__global__ __launch_bounds__(256) void k_csr(
    const unsigned* __restrict__ tmp, const unsigned* __restrict__ rbase,
    int* __restrict__ rp, float* __restrict__ dis,
    unsigned short* __restrict__ csr) {
    __shared__ unsigned lbin[256], lofs[256], lcur[256];
    int b = blockIdx.x, t = threadIdx.x;
    unsigned nb0 = rbase[b], nb1 = rbase[b + 1];
    lbin[t] = 0;
    __syncthreads();
    for (unsigned i = nb0 + t; i < nb1; i += 256)
        atomicAdd(&lbin[tmp[i] >> 16], 1u);
    __syncthreads();
    unsigned c = lbin[t];
    lofs[t] = c;
    __syncthreads();
    for (int off = 1; off < 256; off <<= 1) {
        unsigned v = lofs[t]; unsigned u = (t >= off) ? lofs[t - off] : 0;
        __syncthreads(); lofs[t] = v + u; __syncthreads();
    }
    unsigned r = nb0 + lofs[t] - c;        // exclusive
    int node = b * 256 + t;
    if (node < NN) {
        rp[node] = (int)r;
        dis[node] = rsqrtf((float)c + 1.0f);
    }
    lcur[t] = r;
    __syncthreads();
    for (unsigned i = nb0 + t; i < nb1; i += 256) {
        unsigned rec = tmp[i];
        unsigned pos = atomicAdd(&lcur[rec >> 16], 1u);
        csr[pos] = (unsigned short)(rec & 0xffffu);
    }
    if (b == 0 && t == 0) rp[NN] = NE;
}

// ---------------- standalone conv GEMM for layers 1,2 (half out) ----------------
__global__ __launch_bounds__(256) void k_conv(
    const float* __restrict__ X, const float* __restrict__ W, __half* __restrict__ out) {
    __shared__ float Xs[128][65];
    __shared__ float Ws[64][64];
    gemm_tile<false, true>(X, W, nullptr, out, NN, 0, H, Xs, Ws, blockIdx.x);
}

// ---------------- SpMM + self-term + bias + relu; LAST fuses y = x@lin_W + lin_b ----------------
template <bool LAST>
__global__ __launch_bounds__(256) void k_spmm(
    const int* __restrict__ rp, const unsigned short* __restrict__ csr,
    const float* __restrict__ dis, const __half* __restrict__ xw,
    const float* __restrict__ bias, float* __restrict__ xout,
    const float* __restrict__ lw, const float* __restrict__ lb,
    float* __restrict__ y) {
    int lane = threadIdx.x & 63;
    int warp = threadIdx.x >> 6;
    int d = blockIdx.x * 4 + warp;
    if (d >= NN) return;
    int beg = rp[d], end = rp[d + 1];
    float dd = dis[d];
    float acc0 = dd * __half2float(xw[(size_t)d * H + lane]);
    float acc1 = 0.f, acc2 = 0.f, acc3 = 0.f;
    int n = end - beg; if (n > 64) n = 64;
    int sv = 0; float wv = 0.f;
    if (lane < n) { sv = csr[beg + lane]; wv = dis[sv]; }
    for (int b0 = beg; b0 < end; ) {
        int nb = b0 + 64;
        int n2 = end - nb; if (n2 > 64) n2 = 64;
        int sv2 = 0; float wv2 = 0.f;
        if (n2 > 0 && lane < n2) { sv2 = csr[nb + lane]; wv2 = dis[sv2]; }
        int j = 0;
        for (; j + 3 < n; j += 4) {
            int s0 = __shfl(sv, j);     float w0 = __shfl(wv, j);
            int s1 = __shfl(sv, j + 1); float w1 = __shfl(wv, j + 1);
            int s2 = __shfl(sv, j + 2); float w2 = __shfl(wv, j + 2);
            int s3 = __shfl(sv, j + 3); float w3 = __shfl(wv, j + 3);
            acc0 += w0 * __half2float(xw[(size_t)s0 * H + lane]);
            acc1 += w1 * __half2float(xw[(size_t)s1 * H + lane]);
            acc2 += w2 * __half2float(xw[(size_t)s2 * H + lane]);
            acc3 += w3 * __half2float(xw[(size_t)s3 * H + lane]);
        }
        for (; j < n; ++j) {
            int s0 = __shfl(sv, j); float w0 = __shfl(wv, j);
            acc0 += w0 * __half2float(xw[(size_t)s0 * H + lane]);
        }
        b0 = nb; n = n2; sv = sv2; wv = wv2;
    }
    float v = fmaxf(dd * ((acc0 + acc1) + (acc2 + acc3)) + bias[lane], 0.f);
    if (LAST) {
        float t = v * lw[lane];
        #pragma unroll
        for (int off = 32; off; off >>= 1) t += __shfl_xor(t, off);
        if (lane == 0) y[d] = t + lb[0];
    } else {
        xout[(size_t)d * H + lane] = v;
    }
}

// ---------------- edge scoring: sigmoid(y[src]*y[dst]) ----------------
__global__ void k_out(const float* __restrict__ y, const int* __restrict__ ls,
                      const int* __restrict__ ld, float* __restrict__ out) {
    int e = blockIdx.x * blockDim.x + threadIdx.x;
    if (e < NL) {
        float z = y[ls[e]] * y[ld[e]];
        out[e] = 1.f / (1.f + __expf(-z));
    }
}

static inline size_t up256(size_t x) { return (x + 255) & ~(size_t)255; }

extern "C" void kernel_launch(void* const* d_in, const int* in_sizes, int n_in,
                              void* d_out, int out_size, void* d_ws, size_t ws_size,
                              hipStream_t stream) {
    const float* x_drug = (const float*)d_in[0];
    const float* x_prot = (const float*)d_in[1];
    const float* W_drug = (const float*)d_in[2];
    const float* b_drug = (const float*)d_in[3];
    const float* W_prot = (const float*)d_in[4];
    const float* b_prot = (const float*)d_in[5];
    const float* conv_W = (const float*)d_in[6];
    const float* conv_b = (const float*)d_in[7];
    const float* lin_W  = (const float*)d_in[8];
    const float* lin_b  = (const float*)d_in[9];
    const int*   ei     = (const int*)d_in[10];
    const int*   lsrc   = (const int*)d_in[11];
    const int*   ldst   = (const int*)d_in[12];
    float* out = (float*)d_out;

    char* w = (char*)d_ws;
    size_t off = 0;
    unsigned* bhist = (unsigned*)(w + off); off = up256(off + (size_t)256 * NBK1 * 4);
    unsigned* rsum  = (unsigned*)(w + off); off = up256(off + 256 * 4);
    unsigned* rbase = (unsigned*)(w + off); off = up256(off + 257 * 4);
    unsigned* tmp   = (unsigned*)(w + off); off = up256(off + (size_t)NE * 4);
    unsigned short* csr = (unsigned short*)(w + off); off = up256(off + (size_t)NE * 2);
    int*    rp   = (int*)(w + off);    off = up256(off + (size_t)(NN + 1) * 4);
    float*  dis  = (float*)(w + off);  off = up256(off + (size_t)NN * 4);
    float*  xbuf = (float*)(w + off);  off = up256(off + (size_t)NN * H * 4);
    __half* xwh  = (__half*)(w + off); off = up256(off + (size_t)NN * H * 2);
    float*  y    = (float*)(w + off);  off = up256(off + (size_t)NN * 4);

    // proj_drug || proj_prot || coarse hist (no global atomics, no memset)
    k_front<<<NB_PROJD + NB_PROJP + NBK1, 256, 0, stream>>>(
        x_drug, W_drug, b_drug, x_prot, W_prot, b_prot, ei, bhist, xbuf);

    kA<<<256, 256, 0, stream>>>(bhist, rsum);
    kB<<<1, 256, 0, stream>>>(rsum, rbase);
    kC<<<256, 256, 0, stream>>>(bhist, rbase);

    // bucket partition-scatter || conv GEMM layer 0
    k_part<<<NBK1 + NB_CONV, 256, 0, stream>>>(ei, bhist, tmp, xbuf, conv_W, xwh);

    // per-bucket CSR finalize
    k_csr<<<NB_BKT, 256, 0, stream>>>(tmp, rbase, rp, dis, csr);

    // layer 0
    k_spmm<false><<<(NN + 3) / 4, 256, 0, stream>>>(
        rp, csr, dis, xwh, conv_b, xbuf, nullptr, nullptr, nullptr);
    // layer 1
    k_conv<<<NB_CONV, 256, 0, stream>>>(xbuf, conv_W + (size_t)1 * H * H, xwh);
    k_spmm<false><<<(NN + 3) / 4, 256, 0, stream>>>(
        rp, csr, dis, xwh, conv_b + H, xbuf, nullptr, nullptr, nullptr);
    // layer 2 (fused y epilogue)
    k_conv<<<NB_CONV, 256, 0, stream>>>(xbuf, conv_W + (size_t)2 * H * H, xwh);
    k_spmm<true><<<(NN + 3) / 4, 256, 0, stream>>>(
        rp, csr, dis, xwh, conv_b + 2 * H, nullptr, lin_W, lin_b, y);

    k_out<<<(NL + 255) / 256, 256, 0, stream>>>(y, lsrc, ldst, out);
}

// Round 6
// 224.787 us; speedup vs baseline: 6.1848x; 1.3149x over previous
//
#include <hip/hip_runtime.h>
#include <hip/hip_fp16.h>
#include <math.h>

#define N_DRUG 20000
#define N_PROT 30000
#define NN (N_DRUG + N_PROT)
#define F_DRUG 128
#define F_PROT 256
#define H 64
#define NE 1600000
#define NL 200000

#define NB_PROJD ((N_DRUG + 127) / 128)          // 157 (128 rows/block)
#define NB_PROJP ((N_PROT + 127) / 128)          // 235
#define NB_CONV  ((NN + 255) / 256)              // 196 (256 rows/block)
#define NBK1 256                                  // partition blocks
#define CH   ((NE + NBK1 - 1) / NBK1)            // 6250 edges/block
#define NB_BKT ((NN + 255) / 256)                // 196 buckets

typedef _Float16 half8 __attribute__((ext_vector_type(8)));
typedef float f32x4 __attribute__((ext_vector_type(4)));

#define MFMA16(a, b, c) __builtin_amdgcn_mfma_f32_16x16x32_f16((a), (b), (c), 0, 0, 0)

// ---------------- MFMA projection: out = relu(X@W + b) as fp16 ----------------
// block = 256 thr = 4 waves; tile 128 rows x 64 cols; wave = 32 rows (2 rt).
// A/B frag layout: lane l holds 8 contiguous k at k = kk*32 + 8*(l>>4); A row / B col = l&15.
// C/D: col = l&15, row = (l>>4)*4 + reg.
template <int F>
__device__ __forceinline__ void proj_mfma(
    const float* __restrict__ X, const float* __restrict__ W,
    const float* __restrict__ bias, __half* __restrict__ out,
    int rows, int row_off, _Float16* As /*[128*72]*/, _Float16* Bs /*[64*72]*/,
    int bid) {
    int tid = threadIdx.x;
    int l = tid & 63, wv = tid >> 6;
    int r0 = bid * 128;
    f32x4 acc[2][4];
    #pragma unroll
    for (int i = 0; i < 2; ++i)
        #pragma unroll
        for (int n = 0; n < 4; ++n) acc[i][n] = (f32x4){0.f, 0.f, 0.f, 0.f};

    for (int k0 = 0; k0 < F; k0 += 64) {
        // stage A: 128 rows x 64 k, fp32 -> fp16 (float2 per unit)
        for (int u = tid; u < 128 * 32; u += 256) {
            int r = u >> 5, kp = u & 31;
            int gr = r0 + r;
            float2 v = make_float2(0.f, 0.f);
            if (gr < rows) v = *(const float2*)&X[(size_t)gr * F + k0 + 2 * kp];
            *(__half2*)&As[r * 72 + 2 * kp] = __floats2half2_rn(v.x, v.y);
        }
        // stage B transposed: Bs[c][k] = W[k0+k][c]
        for (int u = tid; u < 64 * 64; u += 256) {
            int k = u >> 6, c = u & 63;
            Bs[c * 72 + k] = (_Float16)W[(size_t)(k0 + k) * H + c];
        }
        __syncthreads();
        half8 bf[2][4];
        #pragma unroll
        for (int kk = 0; kk < 2; ++kk)
            #pragma unroll
            for (int n = 0; n < 4; ++n)
                bf[kk][n] = *(const half8*)&Bs[(n * 16 + (l & 15)) * 72 + kk * 32 + 8 * (l >> 4)];
        #pragma unroll
        for (int rt = 0; rt < 2; ++rt) {
            int arow = wv * 32 + rt * 16 + (l & 15);
            half8 af0 = *(const half8*)&As[arow * 72 + 8 * (l >> 4)];
            half8 af1 = *(const half8*)&As[arow * 72 + 32 + 8 * (l >> 4)];
            #pragma unroll
            for (int n = 0; n < 4; ++n) {
                acc[rt][n] = MFMA16(af0, bf[0][n], acc[rt][n]);
                acc[rt][n] = MFMA16(af1, bf[1][n], acc[rt][n]);
            }
        }
        __syncthreads();
    }
    // epilogue: bias + relu + fp16 store
    #pragma unroll
    for (int rt = 0; rt < 2; ++rt) {
        #pragma unroll
        for (int n = 0; n < 4; ++n) {
            int col = n * 16 + (l & 15);
            float bv = bias[col];
            #pragma unroll
            for (int r = 0; r < 4; ++r) {
                int row = r0 + wv * 32 + rt * 16 + (l >> 4) * 4 + r;
                if (row < rows) {
                    float v = fmaxf(acc[rt][n][r] + bv, 0.f);
                    out[(size_t)(row_off + row) * H + col] = __float2half(v);
                }
            }
        }
    }
}

// ---------------- MFMA conv: xw = x @ Wl (fp16 in/out, fp32 acc). K=64, A direct from global ----------------
__device__ __forceinline__ void conv_mfma(
    const __half* __restrict__ xin, const float* __restrict__ Wl,
    __half* __restrict__ xout, _Float16* Bs /*[64*72]*/, int bid) {
    int tid = threadIdx.x;
    int l = tid & 63, wv = tid >> 6;
    for (int u = tid; u < 64 * 64; u += 256) {
        int k = u >> 6, c = u & 63;
        Bs[c * 72 + k] = (_Float16)Wl[(size_t)k * H + c];
    }
    __syncthreads();
    half8 bf[2][4];
    #pragma unroll
    for (int kk = 0; kk < 2; ++kk)
        #pragma unroll
        for (int n = 0; n < 4; ++n)
            bf[kk][n] = *(const half8*)&Bs[(n * 16 + (l & 15)) * 72 + kk * 32 + 8 * (l >> 4)];
    int r0 = bid * 256 + wv * 64;
    const _Float16* xh = (const _Float16*)xin;
    #pragma unroll
    for (int rt = 0; rt < 4; ++rt) {
        int rbase = r0 + rt * 16;
        int arow = rbase + (l & 15);
        size_t ar = (arow < NN) ? (size_t)arow : 0;
        half8 af0 = *(const half8*)&xh[ar * H + 8 * (l >> 4)];
        half8 af1 = *(const half8*)&xh[ar * H + 32 + 8 * (l >> 4)];
        f32x4 a[4];
        #pragma unroll
        for (int n = 0; n < 4; ++n) {
            a[n] = (f32x4){0.f, 0.f, 0.f, 0.f};
            a[n] = MFMA16(af0, bf[0][n], a[n]);
            a[n] = MFMA16(af1, bf[1][n], a[n]);
        }
        #pragma unroll
        for (int n = 0; n < 4; ++n) {
            int col = n * 16 + (l & 15);
            #pragma unroll
            for (int r = 0; r < 4; ++r) {
                int row = rbase + (l >> 4) * 4 + r;
                if (row < NN) xout[(size_t)row * H + col] = __float2half(a[n][r]);
            }
        }
    }
}

// ---------------- fused front: proj_drug || proj_prot || coarse bucket hist (LDS) ----------------
__global__ __launch_bounds__(256) void k_front(
    const float* __restrict__ xd, const float* __restrict__ Wd, const float* __restrict__ bd,
    const float* __restrict__ xp, const float* __restrict__ Wp, const float* __restrict__ bp,
    const int* __restrict__ ei, unsigned* __restrict__ bhist, __half* __restrict__ xbuf) {
    __shared__ _Float16 As[128 * 72];
    __shared__ _Float16 Bs[64 * 72];
    __shared__ unsigned lh[256];
    int bid = blockIdx.x;
    if (bid < NB_PROJD) {
        proj_mfma<F_DRUG>(xd, Wd, bd, xbuf, N_DRUG, 0, As, Bs, bid);
    } else if (bid < NB_PROJD + NB_PROJP) {
        proj_mfma<F_PROT>(xp, Wp, bp, xbuf, N_PROT, N_DRUG, As, Bs, bid - NB_PROJD);
    } else {
        int blk = bid - NB_PROJD - NB_PROJP;
        int t = threadIdx.x;
        lh[t] = 0;
        __syncthreads();
        int eb = blk * CH, ee = min(NE, eb + CH);
        for (int e = eb + t; e < ee; e += 256)
            atomicAdd(&lh[((unsigned)ei[NE + e]) >> 8], 1u);
        __syncthreads();
        bhist[(size_t)t * NBK1 + blk] = lh[t];
    }
}

// ---------------- scan step A: per-bucket row sums ----------------
__global__ __launch_bounds__(256) void kA(const unsigned* __restrict__ bhist,
                                          unsigned* __restrict__ rsum) {
    __shared__ unsigned s[256];
    int j = blockIdx.x, t = threadIdx.x;
    s[t] = bhist[(size_t)j * NBK1 + t];
    __syncthreads();
    for (int off = 128; off; off >>= 1) {
        if (t < off) s[t] += s[t + off];
        __syncthreads();
    }
    if (t == 0) rsum[j] = s[0];
}

// ---------------- scan step B: exclusive scan of bucket totals ----------------
__global__ __launch_bounds__(256) void kB(const unsigned* __restrict__ rsum,
                                          unsigned* __restrict__ rbase) {
    __shared__ unsigned s[256];
    int t = threadIdx.x;
    unsigned c = rsum[t];
    s[t] = c;
    __syncthreads();
    for (int off = 1; off < 256; off <<= 1) {
        unsigned v = s[t]; unsigned u = (t >= off) ? s[t - off] : 0;
        __syncthreads(); s[t] = v + u; __syncthreads();
    }
    rbase[t] = s[t] - c;
    if (t == 255) rbase[256] = s[255];
}

// ---------------- scan step C: per-bucket row exclusive scan + offset ----------------
__global__ __launch_bounds__(256) void kC(unsigned* __restrict__ bhist,
                                          const unsigned* __restrict__ rbase) {
    __shared__ unsigned s[256];
    int j = blockIdx.x, t = threadIdx.x;
    unsigned c = bhist[(size_t)j * NBK1 + t];
    s[t] = c;
    __syncthreads();
    for (int off = 1; off < 256; off <<= 1) {
        unsigned v = s[t]; unsigned u = (t >= off) ? s[t - off] : 0;
        __syncthreads(); s[t] = v + u; __syncthreads();
    }
    bhist[(size_t)j * NBK1 + t] = rbase[j] + s[t] - c;
}

// ---------------- fused: bucket partition-scatter || conv layer 0 (MFMA) ----------------
__global__ __launch_bounds__(256) void k_part(
    const int* __restrict__ ei, const unsigned* __restrict__ base,
    unsigned* __restrict__ tmp,
    const __half* __restrict__ xbuf, const float* __restrict__ W0,
    __half* __restrict__ xwh) {
    __shared__ _Float16 Bs[64 * 72];
    __shared__ unsigned lcur[256];
    int bid = blockIdx.x;
    if (bid < NBK1) {
        int t = threadIdx.x;
        lcur[t] = base[(size_t)t * NBK1 + bid];
        __syncthreads();
        int eb = bid * CH, ee = min(NE, eb + CH);
        for (int e = eb + t; e < ee; e += 256) {
            unsigned s = (unsigned)ei[e];
            unsigned d = (unsigned)ei[NE + e];
            unsigned pos = atomicAdd(&lcur[d >> 8], 1u);
            tmp[pos] = ((d & 255u) << 16) | s;
        }
    } else {
        conv_mfma(xbuf, W0, xwh, Bs, bid - NBK1);
    }
}

// ---------------- per-bucket CSR finalize: rp, dis, csr(u16) ----------------
__global__ __launch_bounds__(256) void k_csr(
    const unsigned* __restrict__ tmp, const unsigned* __restrict__ rbase,
    int* __restrict__ rp, float* __restrict__ dis,
    unsigned short* __restrict__ csr) {
    __shared__ unsigned lbin[256], lofs[256], lcur[256];
    int b = blockIdx.x, t = threadIdx.x;
    unsigned nb0 = rbase[b], nb1 = rbase[b + 1];
    lbin[t] = 0;
    __syncthreads();
    for (unsigned i = nb0 + t; i < nb1; i += 256)
        atomicAdd(&lbin[tmp[i] >> 16], 1u);
    __syncthreads();
    unsigned c = lbin[t];
    lofs[t] = c;
    __syncthreads();
    for (int off = 1; off < 256; off <<= 1) {
        unsigned v = lofs[t]; unsigned u = (t >= off) ? lofs[t - off] : 0;
        __syncthreads(); lofs[t] = v + u; __syncthreads();
    }
    unsigned r = nb0 + lofs[t] - c;
    int node = b * 256 + t;
    if (node < NN) {
        rp[node] = (int)r;
        dis[node] = rsqrtf((float)c + 1.0f);
    }
    lcur[t] = r;
    __syncthreads();
    for (unsigned i = nb0 + t; i < nb1; i += 256) {
        unsigned rec = tmp[i];
        unsigned pos = atomicAdd(&lcur[rec >> 16], 1u);
        csr[pos] = (unsigned short)(rec & 0xffffu);
    }
    if (b == 0 && t == 0) rp[NN] = NE;
}

// ---------------- standalone conv (layers 1,2) ----------------
__global__ __launch_bounds__(256) void k_conv(
    const __half* __restrict__ X, const float* __restrict__ W, __half* __restrict__ out) {
    __shared__ _Float16 Bs[64 * 72];
    conv_mfma(X, W, out, Bs, blockIdx.x);
}

// ---------------- SpMM + self-term + bias + relu; LAST fuses y = x@lin_W + lin_b ----------------
template <bool LAST>
__global__ __launch_bounds__(256) void k_spmm(
    const int* __restrict__ rp, const unsigned short* __restrict__ csr,
    const float* __restrict__ dis, const __half* __restrict__ xw,
    const float* __restrict__ bias, __half* __restrict__ xout,
    const float* __restrict__ lw, const float* __restrict__ lb,
    float* __restrict__ y) {
    int lane = threadIdx.x & 63;
    int warp = threadIdx.x >> 6;
    int d = blockIdx.x * 4 + warp;
    if (d >= NN) return;
    int beg = rp[d], end = rp[d + 1];
    float dd = dis[d];
    float acc[8];
    acc[0] = dd * __half2float(xw[(size_t)d * H + lane]);
    #pragma unroll
    for (int u = 1; u < 8; ++u) acc[u] = 0.f;
    int n = end - beg; if (n > 64) n = 64;
    int sv = 0; float wv = 0.f;
    if (lane < n) { sv = csr[beg + lane]; wv = dis[sv]; }
    for (int b0 = beg; b0 < end; ) {
        int nb = b0 + 64;
        int n2 = end - nb; if (n2 > 64) n2 = 64;
        int sv2 = 0; float wv2 = 0.f;
        if (n2 > 0 && lane < n2) { sv2 = csr[nb + lane]; wv2 = dis[sv2]; }
        int j = 0;
        for (; j + 7 < n; j += 8) {
            int s[8]; float w[8];
            #pragma unroll
            for (int u = 0; u < 8; ++u) {
                s[u] = __shfl(sv, j + u);
                w[u] = __shfl(wv, j + u);
            }
            #pragma unroll
            for (int u = 0; u < 8; ++u)
                acc[u] += w[u] * __half2float(xw[(size_t)s[u] * H + lane]);
        }
        for (; j < n; ++j) {
            int s0 = __shfl(sv, j); float w0 = __shfl(wv, j);
            acc[0] += w0 * __half2float(xw[(size_t)s0 * H + lane]);
        }
        b0 = nb; n = n2; sv = sv2; wv = wv2;
    }
    float v = ((acc[0] + acc[1]) + (acc[2] + acc[3])) + ((acc[4] + acc[5]) + (acc[6] + acc[7]));
    v = fmaxf(dd * v + bias[lane], 0.f);
    if (LAST) {
        float t = v * lw[lane];
        #pragma unroll
        for (int off = 32; off; off >>= 1) t += __shfl_xor(t, off);
        if (lane == 0) y[d] = t + lb[0];
    } else {
        xout[(size_t)d * H + lane] = __float2half(v);
    }
}

// ---------------- edge scoring: sigmoid(y[src]*y[dst]) ----------------
__global__ void k_out(const float* __restrict__ y, const int* __restrict__ ls,
                      const int* __restrict__ ld, float* __restrict__ out) {
    int e = blockIdx.x * blockDim.x + threadIdx.x;
    if (e < NL) {
        float z = y[ls[e]] * y[ld[e]];
        out[e] = 1.f / (1.f + __expf(-z));
    }
}

static inline size_t up256(size_t x) { return (x + 255) & ~(size_t)255; }

extern "C" void kernel_launch(void* const* d_in, const int* in_sizes, int n_in,
                              void* d_out, int out_size, void* d_ws, size_t ws_size,
                              hipStream_t stream) {
    const float* x_drug = (const float*)d_in[0];
    const float* x_prot = (const float*)d_in[1];
    const float* W_drug = (const float*)d_in[2];
    const float* b_drug = (const float*)d_in[3];
    const float* W_prot = (const float*)d_in[4];
    const float* b_prot = (const float*)d_in[5];
    const float* conv_W = (const float*)d_in[6];
    const float* conv_b = (const float*)d_in[7];
    const float* lin_W  = (const float*)d_in[8];
    const float* lin_b  = (const float*)d_in[9];
    const int*   ei     = (const int*)d_in[10];
    const int*   lsrc   = (const int*)d_in[11];
    const int*   ldst   = (const int*)d_in[12];
    float* out = (float*)d_out;

    char* w = (char*)d_ws;
    size_t off = 0;
    unsigned* bhist = (unsigned*)(w + off); off = up256(off + (size_t)256 * NBK1 * 4);
    unsigned* rsum  = (unsigned*)(w + off); off = up256(off + 256 * 4);
    unsigned* rbase = (unsigned*)(w + off); off = up256(off + 257 * 4);
    unsigned* tmp   = (unsigned*)(w + off); off = up256(off + (size_t)NE * 4);
    unsigned short* csr = (unsigned short*)(w + off); off = up256(off + (size_t)NE * 2);
    int*    rp   = (int*)(w + off);    off = up256(off + (size_t)(NN + 1) * 4);
    float*  dis  = (float*)(w + off);  off = up256(off + (size_t)NN * 4);
    __half* xbuf = (__half*)(w + off); off = up256(off + (size_t)NN * H * 2);
    __half* xwh  = (__half*)(w + off); off = up256(off + (size_t)NN * H * 2);
    float*  y    = (float*)(w + off);  off = up256(off + (size_t)NN * 4);

    // proj_drug || proj_prot || coarse hist
    k_front<<<NB_PROJD + NB_PROJP + NBK1, 256, 0, stream>>>(
        x_drug, W_drug, b_drug, x_prot, W_prot, b_prot, ei, bhist, xbuf);

    kA<<<256, 256, 0, stream>>>(bhist, rsum);
    kB<<<1, 256, 0, stream>>>(rsum, rbase);
    kC<<<256, 256, 0, stream>>>(bhist, rbase);

    // bucket partition-scatter || conv layer 0 (MFMA)
    k_part<<<NBK1 + NB_CONV, 256, 0, stream>>>(ei, bhist, tmp, xbuf, conv_W, xwh);

    // per-bucket CSR finalize
    k_csr<<<NB_BKT, 256, 0, stream>>>(tmp, rbase, rp, dis, csr);

    // layer 0
    k_spmm<false><<<(NN + 3) / 4, 256, 0, stream>>>(
        rp, csr, dis, xwh, conv_b, xbuf, nullptr, nullptr, nullptr);
    // layer 1
    k_conv<<<NB_CONV, 256, 0, stream>>>(xbuf, conv_W + (size_t)1 * H * H, xwh);
    k_spmm<false><<<(NN + 3) / 4, 256, 0, stream>>>(
        rp, csr, dis, xwh, conv_b + H, xbuf, nullptr, nullptr, nullptr);
    // layer 2 (fused y epilogue)
    k_conv<<<NB_CONV, 256, 0, stream>>>(xbuf, conv_W + (size_t)2 * H * H, xwh);
    k_spmm<true><<<(NN + 3) / 4, 256, 0, stream>>>(
        rp, csr, dis, xwh, conv_b + 2 * H, nullptr, lin_W, lin_b, y);

    k_out<<<(NL + 255) / 256, 256, 0, stream>>>(y, lsrc, ldst, out);
}

// Round 7
// 208.116 us; speedup vs baseline: 6.6802x; 1.0801x over previous
//
#include <hip/hip_runtime.h>
#include <hip/hip_fp16.h>
#include <math.h>

#define N_DRUG 20000
#define N_PROT 30000
#define NN (N_DRUG + N_PROT)
#define F_DRUG 128
#define F_PROT 256
#define H 64
#define NE 1600000
#define NL 200000

#define NB_PROJD ((N_DRUG + 127) / 128)          // 157 (128 rows/block)
#define NB_PROJP ((N_PROT + 127) / 128)          // 235
#define NB_CONV  ((NN + 255) / 256)              // 196 (256 rows/block)
#define NBK1 256                                  // partition blocks
#define CH   ((NE + NBK1 - 1) / NBK1)            // 6250 edges/block
#define NB_BKT ((NN + 255) / 256)                // 196 buckets

typedef _Float16 h8 __attribute__((ext_vector_type(8)));
typedef _Float16 h4 __attribute__((ext_vector_type(4)));
typedef float f32x4 __attribute__((ext_vector_type(4)));

#define MFMA16(a, b, c) __builtin_amdgcn_mfma_f32_16x16x32_f16((a), (b), (c), 0, 0, 0)

// ---------------- weight prep: transpose + fp16 ([c][k] layout) ----------------
__global__ __launch_bounds__(256) void k_wprep(
    const float* __restrict__ Wd, const float* __restrict__ Wp,
    const float* __restrict__ cw,
    _Float16* __restrict__ wdt, _Float16* __restrict__ wpt,
    _Float16* __restrict__ cwt) {
    int i = blockIdx.x * 256 + threadIdx.x;
    if (i < 64 * F_DRUG) {
        int c = i / F_DRUG, k = i % F_DRUG;
        wdt[i] = (_Float16)Wd[k * H + c];
    }
    if (i < 64 * F_PROT) {
        int c = i / F_PROT, k = i % F_PROT;
        wpt[i] = (_Float16)Wp[k * H + c];
    }
    if (i < 3 * 64 * 64) {
        int l = i >> 12, r = i & 4095;
        int c = r >> 6, k = r & 63;
        cwt[i] = (_Float16)cw[(l << 12) + k * H + c];
    }
}

// ---------------- zero-LDS MFMA projection: out = relu(X@W + b) as fp16 ----------------
// Swapped operands: A = Wt (c-major, L1-hot), B = X (row-major contig k). D[c][r].
// block = 4 waves x 32 rows = 128 rows; per wave 2 rt of 16 rows.
template <int F>
__device__ __forceinline__ void proj_direct(
    const float* __restrict__ X, const _Float16* __restrict__ Wt,
    const float* __restrict__ bias, __half* __restrict__ out,
    int rows, int row_off, int bid) {
    int l = threadIdx.x & 63, wvi = threadIdx.x >> 6;
    int lr = l & 15, lq = l >> 4;
    int r0 = bid * 128 + wvi * 32;
    f32x4 acc[2][4];
    #pragma unroll
    for (int rt = 0; rt < 2; ++rt)
        #pragma unroll
        for (int n = 0; n < 4; ++n) acc[rt][n] = (f32x4){0.f, 0.f, 0.f, 0.f};

    for (int k0 = 0; k0 < F; k0 += 64) {
        h8 af[4][2];
        #pragma unroll
        for (int n = 0; n < 4; ++n)
            #pragma unroll
            for (int kk = 0; kk < 2; ++kk)
                af[n][kk] = *(const h8*)&Wt[(size_t)(n * 16 + lr) * F + k0 + kk * 32 + lq * 8];
        #pragma unroll
        for (int rt = 0; rt < 2; ++rt) {
            int r = r0 + rt * 16 + lr;
            int rc = (r < rows) ? r : (rows - 1);
            h8 bf[2];
            #pragma unroll
            for (int kk = 0; kk < 2; ++kk) {
                const float* xp = X + (size_t)rc * F + k0 + kk * 32 + lq * 8;
                float4 a = *(const float4*)xp;
                float4 b = *(const float4*)(xp + 4);
                h8 t;
                t[0] = (_Float16)a.x; t[1] = (_Float16)a.y;
                t[2] = (_Float16)a.z; t[3] = (_Float16)a.w;
                t[4] = (_Float16)b.x; t[5] = (_Float16)b.y;
                t[6] = (_Float16)b.z; t[7] = (_Float16)b.w;
                bf[kk] = t;
            }
            #pragma unroll
            for (int n = 0; n < 4; ++n) {
                acc[rt][n] = MFMA16(af[n][0], bf[0], acc[rt][n]);
                acc[rt][n] = MFMA16(af[n][1], bf[1], acc[rt][n]);
            }
        }
    }
    #pragma unroll
    for (int rt = 0; rt < 2; ++rt) {
        int r = r0 + rt * 16 + lr;
        if (r < rows) {
            #pragma unroll
            for (int n = 0; n < 4; ++n) {
                int c = n * 16 + lq * 4;
                float4 bv = *(const float4*)&bias[c];
                h4 hv;
                hv[0] = (_Float16)fmaxf(acc[rt][n][0] + bv.x, 0.f);
                hv[1] = (_Float16)fmaxf(acc[rt][n][1] + bv.y, 0.f);
                hv[2] = (_Float16)fmaxf(acc[rt][n][2] + bv.z, 0.f);
                hv[3] = (_Float16)fmaxf(acc[rt][n][3] + bv.w, 0.f);
                *(h4*)((_Float16*)out + (size_t)(row_off + r) * H + c) = hv;
            }
        }
    }
}

// ---------------- zero-LDS MFMA conv: xw = x @ Wl (fp16 in/out, fp32 acc) ----------------
// block = 4 waves x 64 rows = 256 rows.
__device__ __forceinline__ void conv_direct(
    const __half* __restrict__ xin, const _Float16* __restrict__ Wt,
    __half* __restrict__ xout, int bid) {
    int l = threadIdx.x & 63, wvi = threadIdx.x >> 6;
    int lr = l & 15, lq = l >> 4;
    const _Float16* xh = (const _Float16*)xin;
    h8 af[4][2];
    #pragma unroll
    for (int n = 0; n < 4; ++n)
        #pragma unroll
        for (int kk = 0; kk < 2; ++kk)
            af[n][kk] = *(const h8*)&Wt[(size_t)(n * 16 + lr) * 64 + kk * 32 + lq * 8];
    int r0 = bid * 256 + wvi * 64;
    #pragma unroll
    for (int rt = 0; rt < 4; ++rt) {
        int r = r0 + rt * 16 + lr;
        int rc = (r < NN) ? r : (NN - 1);
        h8 bf0 = *(const h8*)&xh[(size_t)rc * H + lq * 8];
        h8 bf1 = *(const h8*)&xh[(size_t)rc * H + 32 + lq * 8];
        f32x4 a[4];
        #pragma unroll
        for (int n = 0; n < 4; ++n) {
            a[n] = (f32x4){0.f, 0.f, 0.f, 0.f};
            a[n] = MFMA16(af[n][0], bf0, a[n]);
            a[n] = MFMA16(af[n][1], bf1, a[n]);
        }
        if (r < NN) {
            #pragma unroll
            for (int n = 0; n < 4; ++n) {
                int c = n * 16 + lq * 4;
                h4 hv;
                hv[0] = (_Float16)a[n][0]; hv[1] = (_Float16)a[n][1];
                hv[2] = (_Float16)a[n][2]; hv[3] = (_Float16)a[n][3];
                *(h4*)((_Float16*)xout + (size_t)r * H + c) = hv;
            }
        }
    }
}

// ---------------- fused front: proj_drug || proj_prot || coarse bucket hist ----------------
__global__ __launch_bounds__(256) void k_front(
    const float* __restrict__ xd, const _Float16* __restrict__ wdt, const float* __restrict__ bd,
    const float* __restrict__ xp, const _Float16* __restrict__ wpt, const float* __restrict__ bp,
    const int* __restrict__ ei, unsigned* __restrict__ bhist, __half* __restrict__ xbuf) {
    __shared__ unsigned lh[256];
    int bid = blockIdx.x;
    if (bid < NB_PROJD) {
        proj_direct<F_DRUG>(xd, wdt, bd, xbuf, N_DRUG, 0, bid);
    } else if (bid < NB_PROJD + NB_PROJP) {
        proj_direct<F_PROT>(xp, wpt, bp, xbuf, N_PROT, N_DRUG, bid - NB_PROJD);
    } else {
        int blk = bid - NB_PROJD - NB_PROJP;
        int t = threadIdx.x;
        lh[t] = 0;
        __syncthreads();
        int eb = blk * CH, ee = min(NE, eb + CH);
        for (int e = eb + t; e < ee; e += 256)
            atomicAdd(&lh[((unsigned)ei[NE + e]) >> 8], 1u);
        __syncthreads();
        bhist[(size_t)t * NBK1 + blk] = lh[t];
    }
}

// ---------------- scan step A: per-bucket row sums ----------------
__global__ __launch_bounds__(256) void kA(const unsigned* __restrict__ bhist,
                                          unsigned* __restrict__ rsum) {
    __shared__ unsigned s[256];
    int j = blockIdx.x, t = threadIdx.x;
    s[t] = bhist[(size_t)j * NBK1 + t];
    __syncthreads();
    for (int off = 128; off; off >>= 1) {
        if (t < off) s[t] += s[t + off];
        __syncthreads();
    }
    if (t == 0) rsum[j] = s[0];
}

// ---------------- scan step B: exclusive scan of bucket totals ----------------
__global__ __launch_bounds__(256) void kB(const unsigned* __restrict__ rsum,
                                          unsigned* __restrict__ rbase) {
    __shared__ unsigned s[256];
    int t = threadIdx.x;
    unsigned c = rsum[t];
    s[t] = c;
    __syncthreads();
    for (int off = 1; off < 256; off <<= 1) {
        unsigned v = s[t]; unsigned u = (t >= off) ? s[t - off] : 0;
        __syncthreads(); s[t] = v + u; __syncthreads();
    }
    rbase[t] = s[t] - c;
    if (t == 255) rbase[256] = s[255];
}

// ---------------- scan step C: per-bucket row exclusive scan + offset ----------------
__global__ __launch_bounds__(256) void kC(unsigned* __restrict__ bhist,
                                          const unsigned* __restrict__ rbase) {
    __shared__ unsigned s[256];
    int j = blockIdx.x, t = threadIdx.x;
    unsigned c = bhist[(size_t)j * NBK1 + t];
    s[t] = c;
    __syncthreads();
    for (int off = 1; off < 256; off <<= 1) {
        unsigned v = s[t]; unsigned u = (t >= off) ? s[t - off] : 0;
        __syncthreads(); s[t] = v + u; __syncthreads();
    }
    bhist[(size_t)j * NBK1 + t] = rbase[j] + s[t] - c;
}

// ---------------- fused: bucket partition-scatter || conv layer 0 ----------------
__global__ __launch_bounds__(256) void k_part(
    const int* __restrict__ ei, const unsigned* __restrict__ base,
    unsigned* __restrict__ tmp,
    const __half* __restrict__ xbuf, const _Float16* __restrict__ cwt,
    __half* __restrict__ xwh) {
    __shared__ unsigned lcur[256];
    int bid = blockIdx.x;
    if (bid < NBK1) {
        int t = threadIdx.x;
        lcur[t] = base[(size_t)t * NBK1 + bid];
        __syncthreads();
        int eb = bid * CH, ee = min(NE, eb + CH);
        for (int e = eb + t; e < ee; e += 256) {
            unsigned s = (unsigned)ei[e];
            unsigned d = (unsigned)ei[NE + e];
            unsigned pos = atomicAdd(&lcur[d >> 8], 1u);
            tmp[pos] = ((d & 255u) << 16) | s;
        }
    } else {
        conv_direct(xbuf, cwt, xwh, bid - NBK1);
    }
}

// ---------------- per-bucket CSR finalize: rp, dis, csr(u16) ----------------
__global__ __launch_bounds__(256) void k_csr(
    const unsigned* __restrict__ tmp, const unsigned* __restrict__ rbase,
    int* __restrict__ rp, float* __restrict__ dis,
    unsigned short* __restrict__ csr) {
    __shared__ unsigned lbin[256], lofs[256], lcur[256];
    int b = blockIdx.x, t = threadIdx.x;
    unsigned nb0 = rbase[b], nb1 = rbase[b + 1];
    lbin[t] = 0;
    __syncthreads();
    for (unsigned i = nb0 + t; i < nb1; i += 256)
        atomicAdd(&lbin[tmp[i] >> 16], 1u);
    __syncthreads();
    unsigned c = lbin[t];
    lofs[t] = c;
    __syncthreads();
    for (int off = 1; off < 256; off <<= 1) {
        unsigned v = lofs[t]; unsigned u = (t >= off) ? lofs[t - off] : 0;
        __syncthreads(); lofs[t] = v + u; __syncthreads();
    }
    unsigned r = nb0 + lofs[t] - c;
    int node = b * 256 + t;
    if (node < NN) {
        rp[node] = (int)r;
        dis[node] = rsqrtf((float)c + 1.0f);
    }
    lcur[t] = r;
    __syncthreads();
    for (unsigned i = nb0 + t; i < nb1; i += 256) {
        unsigned rec = tmp[i];
        unsigned pos = atomicAdd(&lcur[rec >> 16], 1u);
        csr[pos] = (unsigned short)(rec & 0xffffu);
    }
    if (b == 0 && t == 0) rp[NN] = NE;
}

// ---------------- standalone conv (layers 1,2) ----------------
__global__ __launch_bounds__(256) void k_conv(
    const __half* __restrict__ X, const _Float16* __restrict__ Wt, __half* __restrict__ out) {
    conv_direct(X, Wt, out, blockIdx.x);
}

// ---------------- SpMM quarter-wave: 4 edges/step, half4 per lane ----------------
// lane: q = lane>>4 (edge slot), g = lane&15 (features 4g..4g+3).
template <bool LAST>
__global__ __launch_bounds__(256) void k_spmm(
    const int* __restrict__ rp, const unsigned short* __restrict__ csr,
    const float* __restrict__ dis, const __half* __restrict__ xw,
    const float* __restrict__ bias, __half* __restrict__ xout,
    const float* __restrict__ lw, const float* __restrict__ lb,
    float* __restrict__ y) {
    int lane = threadIdx.x & 63;
    int wrp = threadIdx.x >> 6;
    int d = blockIdx.x * 4 + wrp;
    if (d >= NN) return;
    int q = lane >> 4, g = lane & 15;
    int beg = rp[d], end = rp[d + 1];
    float dd = dis[d];
    const _Float16* xh = (const _Float16*)xw;
    float ax = 0.f, ay = 0.f, az = 0.f, aw = 0.f;

    int n = end - beg; if (n > 64) n = 64;
    int sv = 0; float wv = 0.f;
    if (lane < n) { sv = csr[beg + lane]; wv = dis[sv]; }
    for (int b0 = beg; b0 < end; ) {
        int nb = b0 + 64;
        int n2 = end - nb; if (n2 > 64) n2 = 64;
        int sv2 = 0; float wv2 = 0.f;
        if (n2 > 0 && lane < n2) { sv2 = csr[nb + lane]; wv2 = dis[sv2]; }
        int nsteps = (n + 3) >> 2;
        #pragma unroll 4
        for (int jj = 0; jj < nsteps; ++jj) {
            int idx = jj * 4 + q;
            int s = __shfl(sv, idx);      // w==0 masks idx >= n
            float w = __shfl(wv, idx);
            h4 xv = *(const h4*)&xh[((unsigned)s << 6) + (g << 2)];
            ax += w * (float)xv[0];
            ay += w * (float)xv[1];
            az += w * (float)xv[2];
            aw += w * (float)xv[3];
        }
        b0 = nb; n = n2; sv = sv2; wv = wv2;
    }
    // reduce across the 4 quarters (all lanes end with full sums for group g)
    ax += __shfl_xor(ax, 16); ay += __shfl_xor(ay, 16);
    az += __shfl_xor(az, 16); aw += __shfl_xor(aw, 16);
    ax += __shfl_xor(ax, 32); ay += __shfl_xor(ay, 32);
    az += __shfl_xor(az, 32); aw += __shfl_xor(aw, 32);

    // epilogue: self term + bias + relu
    h4 xs = *(const h4*)&xh[((unsigned)d << 6) + (g << 2)];
    float4 bv = *(const float4*)&bias[g << 2];
    float sn = dd * dd;
    float vx = fmaxf(dd * ax + sn * (float)xs[0] + bv.x, 0.f);
    float vy = fmaxf(dd * ay + sn * (float)xs[1] + bv.y, 0.f);
    float vz = fmaxf(dd * az + sn * (float)xs[2] + bv.z, 0.f);
    float vw = fmaxf(dd * aw + sn * (float)xs[3] + bv.w, 0.f);
    if (LAST) {
        float4 lv = *(const float4*)&lw[g << 2];
        float t = vx * lv.x + vy * lv.y + vz * lv.z + vw * lv.w;
        #pragma unroll
        for (int off = 8; off; off >>= 1) t += __shfl_xor(t, off);
        if (lane == 0) y[d] = t + lb[0];
    } else if (q == 0) {
        h4 hv;
        hv[0] = (_Float16)vx; hv[1] = (_Float16)vy;
        hv[2] = (_Float16)vz; hv[3] = (_Float16)vw;
        *(h4*)((_Float16*)xout + ((size_t)d << 6) + (g << 2)) = hv;
    }
}

// ---------------- edge scoring: sigmoid(y[src]*y[dst]) ----------------
__global__ void k_out(const float* __restrict__ y, const int* __restrict__ ls,
                      const int* __restrict__ ld, float* __restrict__ out) {
    int e = blockIdx.x * blockDim.x + threadIdx.x;
    if (e < NL) {
        float z = y[ls[e]] * y[ld[e]];
        out[e] = 1.f / (1.f + __expf(-z));
    }
}

static inline size_t up256(size_t x) { return (x + 255) & ~(size_t)255; }

extern "C" void kernel_launch(void* const* d_in, const int* in_sizes, int n_in,
                              void* d_out, int out_size, void* d_ws, size_t ws_size,
                              hipStream_t stream) {
    const float* x_drug = (const float*)d_in[0];
    const float* x_prot = (const float*)d_in[1];
    const float* W_drug = (const float*)d_in[2];
    const float* b_drug = (const float*)d_in[3];
    const float* W_prot = (const float*)d_in[4];
    const float* b_prot = (const float*)d_in[5];
    const float* conv_W = (const float*)d_in[6];
    const float* conv_b = (const float*)d_in[7];
    const float* lin_W  = (const float*)d_in[8];
    const float* lin_b  = (const float*)d_in[9];
    const int*   ei     = (const int*)d_in[10];
    const int*   lsrc   = (const int*)d_in[11];
    const int*   ldst   = (const int*)d_in[12];
    float* out = (float*)d_out;

    char* w = (char*)d_ws;
    size_t off = 0;
    unsigned* bhist = (unsigned*)(w + off); off = up256(off + (size_t)256 * NBK1 * 4);
    unsigned* rsum  = (unsigned*)(w + off); off = up256(off + 256 * 4);
    unsigned* rbase = (unsigned*)(w + off); off = up256(off + 257 * 4);
    unsigned* tmp   = (unsigned*)(w + off); off = up256(off + (size_t)NE * 4);
    unsigned short* csr = (unsigned short*)(w + off); off = up256(off + (size_t)NE * 2);
    int*    rp   = (int*)(w + off);    off = up256(off + (size_t)(NN + 1) * 4);
    float*  dis  = (float*)(w + off);  off = up256(off + (size_t)NN * 4);
    __half* xbuf = (__half*)(w + off); off = up256(off + (size_t)NN * H * 2);
    __half* xwh  = (__half*)(w + off); off = up256(off + (size_t)NN * H * 2);
    float*  y    = (float*)(w + off);  off = up256(off + (size_t)NN * 4);
    _Float16* wdt = (_Float16*)(w + off); off = up256(off + (size_t)64 * F_DRUG * 2);
    _Float16* wpt = (_Float16*)(w + off); off = up256(off + (size_t)64 * F_PROT * 2);
    _Float16* cwt = (_Float16*)(w + off); off = up256(off + (size_t)3 * 64 * 64 * 2);

    k_wprep<<<64, 256, 0, stream>>>(W_drug, W_prot, conv_W, wdt, wpt, cwt);

    // proj_drug || proj_prot || coarse hist
    k_front<<<NB_PROJD + NB_PROJP + NBK1, 256, 0, stream>>>(
        x_drug, wdt, b_drug, x_prot, wpt, b_prot, ei, bhist, xbuf);

    kA<<<256, 256, 0, stream>>>(bhist, rsum);
    kB<<<1, 256, 0, stream>>>(rsum, rbase);
    kC<<<256, 256, 0, stream>>>(bhist, rbase);

    // bucket partition-scatter || conv layer 0
    k_part<<<NBK1 + NB_CONV, 256, 0, stream>>>(ei, bhist, tmp, xbuf, cwt, xwh);

    // per-bucket CSR finalize
    k_csr<<<NB_BKT, 256, 0, stream>>>(tmp, rbase, rp, dis, csr);

    // layer 0
    k_spmm<false><<<(NN + 3) / 4, 256, 0, stream>>>(
        rp, csr, dis, xwh, conv_b, xbuf, nullptr, nullptr, nullptr);
    // layer 1
    k_conv<<<NB_CONV, 256, 0, stream>>>(xbuf, cwt + 4096, xwh);
    k_spmm<false><<<(NN + 3) / 4, 256, 0, stream>>>(
        rp, csr, dis, xwh, conv_b + H, xbuf, nullptr, nullptr, nullptr);
    // layer 2 (fused y epilogue)
    k_conv<<<NB_CONV, 256, 0, stream>>>(xbuf, cwt + 8192, xwh);
    k_spmm<true><<<(NN + 3) / 4, 256, 0, stream>>>(
        rp, csr, dis, xwh, conv_b + 2 * H, nullptr, lin_W, lin_b, y);

    k_out<<<(NL + 255) / 256, 256, 0, stream>>>(y, lsrc, ldst, out);
}